// Round 1
// baseline (42716.080 us; speedup 1.0000x reference)
//
#include <hip/hip_runtime.h>

#define S_LEN 128
#define T_LEN 64
#define BSZ   64
#define EMBD  256
#define HID_  512
#define DHID_ 1024
#define VOC_  32000

// ---------------- workspace layout (float offsets) ----------------
#define WS_X0   0ull
#define WS_XCAT (WS_X0   + (size_t)S_LEN * BSZ * EMBD)        //  2,097,152
#define WS_XWA  (WS_XCAT + (size_t)S_LEN * BSZ * (2 * HID_))  // 10,485,760
#define WS_XWB  (WS_XWA  + (size_t)S_LEN * BSZ * (4 * HID_))  // 27,262,976
#define WS_HBUF (WS_XWB  + (size_t)S_LEN * BSZ * (4 * HID_))  // 44,040,192
#define WS_HS   (WS_HBUF + (size_t)4 * BSZ * DHID_)           // 44,302,336
#define WS_CS   (WS_HS   + (size_t)2 * BSZ * DHID_)           // 44,433,408
#define WS_BAR  (WS_CS   + (size_t)2 * BSZ * DHID_)           // 44,564,480

// ---------------- embedding gathers ----------------
__global__ __launch_bounds__(64) void embed_src_kernel(
    const int* __restrict__ toks, const float* __restrict__ emb,
    float* __restrict__ out)
{
    const int i = blockIdx.x;                    // token index = t*B + b
    const int tok = toks[i];
    const float4* src = reinterpret_cast<const float4*>(emb + (size_t)tok * EMBD);
    float4* dst = reinterpret_cast<float4*>(out + (size_t)i * EMBD);
    dst[threadIdx.x] = src[threadIdx.x];
}

__global__ __launch_bounds__(64) void embed_dec_kernel(
    const int* __restrict__ sent, const int* __restrict__ targ,
    const float* __restrict__ emb, float* __restrict__ out)
{
    const int i = blockIdx.x;                    // t*B + b,  t in [0,64)
    const int t = i >> 6, b = i & 63;
    const int tok = (t == 0) ? sent[(S_LEN - 1) * BSZ + b] : targ[(t - 1) * BSZ + b];
    const float4* src = reinterpret_cast<const float4*>(emb + (size_t)tok * EMBD);
    float4* dst = reinterpret_cast<float4*>(out + (size_t)i * EMBD);
    dst[threadIdx.x] = src[threadIdx.x];
}

// ---------------- fp32 GEMM:  C[M,N] = A[M,K] * B[N,K]^T + b1[N] (+ b2[N]) ----------------
// M,N multiples of 64; K multiple of 16.
__global__ __launch_bounds__(256) void gemm_bias_kernel(
    const float* __restrict__ A, const float* __restrict__ B,
    const float* __restrict__ b1, const float* __restrict__ b2,
    float* __restrict__ C, int M, int N, int K)
{
    __shared__ __align__(16) float As[16][64];
    __shared__ __align__(16) float Bs[16][64];
    const int tid = threadIdx.x;
    const int bn = blockIdx.x * 64;
    const int bm = blockIdx.y * 64;
    const int tx = tid & 15;          // 4-col group
    const int ty = tid >> 4;          // 4-row group
    const int r  = tid >> 2;          // staging row 0..63
    const int kq = (tid & 3) << 2;    // staging k quad 0,4,8,12

    float acc[4][4] = {{0.f,0.f,0.f,0.f},{0.f,0.f,0.f,0.f},
                       {0.f,0.f,0.f,0.f},{0.f,0.f,0.f,0.f}};

    for (int k0 = 0; k0 < K; k0 += 16) {
        const float4 a4 = *reinterpret_cast<const float4*>(&A[(size_t)(bm + r) * K + k0 + kq]);
        const float4 b4 = *reinterpret_cast<const float4*>(&B[(size_t)(bn + r) * K + k0 + kq]);
        __syncthreads();
        As[kq + 0][r] = a4.x; As[kq + 1][r] = a4.y; As[kq + 2][r] = a4.z; As[kq + 3][r] = a4.w;
        Bs[kq + 0][r] = b4.x; Bs[kq + 1][r] = b4.y; Bs[kq + 2][r] = b4.z; Bs[kq + 3][r] = b4.w;
        __syncthreads();
#pragma unroll
        for (int k = 0; k < 16; ++k) {
            const float4 av = *reinterpret_cast<const float4*>(&As[k][ty << 2]);
            const float4 bv = *reinterpret_cast<const float4*>(&Bs[k][tx << 2]);
            const float a0 = av.x, a1 = av.y, a2 = av.z, a3 = av.w;
            const float c0 = bv.x, c1 = bv.y, c2 = bv.z, c3 = bv.w;
            acc[0][0] += a0 * c0; acc[0][1] += a0 * c1; acc[0][2] += a0 * c2; acc[0][3] += a0 * c3;
            acc[1][0] += a1 * c0; acc[1][1] += a1 * c1; acc[1][2] += a1 * c2; acc[1][3] += a1 * c3;
            acc[2][0] += a2 * c0; acc[2][1] += a2 * c1; acc[2][2] += a2 * c2; acc[2][3] += a2 * c3;
            acc[3][0] += a3 * c0; acc[3][1] += a3 * c1; acc[3][2] += a3 * c2; acc[3][3] += a3 * c3;
        }
    }
#pragma unroll
    for (int i = 0; i < 4; ++i) {
        const int row = bm + (ty << 2) + i;
#pragma unroll
        for (int j = 0; j < 4; ++j) {
            const int col = bn + (tx << 2) + j;
            float v = acc[i][j] + b1[col];
            if (b2) v += b2[col];
            C[(size_t)row * N + col] = v;
        }
    }
}

// ---------------- grid barrier (all 256 blocks resident: LDS 82KB -> 1 block/CU) ----------------
__device__ __forceinline__ void grid_barrier(int* cnt, int* gen, int nb)
{
    __syncthreads();
    __threadfence();                          // release: flush h writes to coherence point
    if (threadIdx.x == 0) {
        const int g = __hip_atomic_load(gen, __ATOMIC_RELAXED, __HIP_MEMORY_SCOPE_AGENT);
        const int t = __hip_atomic_fetch_add(cnt, 1, __ATOMIC_ACQ_REL, __HIP_MEMORY_SCOPE_AGENT);
        if (t == nb - 1) {
            __hip_atomic_store(cnt, 0, __ATOMIC_RELAXED, __HIP_MEMORY_SCOPE_AGENT);
            __hip_atomic_fetch_add(gen, 1, __ATOMIC_RELEASE, __HIP_MEMORY_SCOPE_AGENT);
        } else {
            while (__hip_atomic_load(gen, __ATOMIC_RELAXED, __HIP_MEMORY_SCOPE_AGENT) == g)
                __builtin_amdgcn_s_sleep(1);
        }
    }
    __syncthreads();
    __threadfence();                          // acquire: invalidate stale L1/L2 lines
}

__device__ __forceinline__ float sigmoidf_(float x) { return 1.f / (1.f + expf(-x)); }

// ---------------- persistent LSTM scan ----------------
// Grid must be 256 blocks x 256 threads. ndir*H must equal 1024 (=256 blocks * 4 cells).
// xw: (T,B,4H) precomputed x@Wih^T + bih + bhh, gate chunks i,f,g,o.
// hbuf: double-buffered h per dir: [(dir*2+phase)*B*H].
// h0/c0: optional initial state, layout (B,H) (decoder: H==DHID). y_out: (T,B,y_stride),
// col offset dir*H. hs_dst/cs_dst: optional final state, layout (B,DHID), col dir*H.
__global__ __launch_bounds__(256, 1) void lstm_scan_kernel(
    const float* __restrict__ xw0, const float* __restrict__ xw1,
    const float* __restrict__ Whh0, const float* __restrict__ Whh1,
    float* __restrict__ hbuf,
    const float* __restrict__ h0, const float* __restrict__ c0,
    float* __restrict__ y_out, int y_stride,
    float* __restrict__ hs_dst, float* __restrict__ cs_dst,
    int T, int H, int ndir, int rev_mask,
    int* bar_cnt, int* bar_gen)
{
    __shared__ __align__(16) float Whh_s[16 * DHID_];   // 64 KB max
    __shared__ float ht[64][65];                        // 16.6 KB

    const int tid = threadIdx.x;
    const int nb  = gridDim.x;
    const int bpd = nb / ndir;
    const int dir = blockIdx.x / bpd;
    const int blk = blockIdx.x % bpd;
    const int m0  = blk * 4;
    const int b   = tid & 63;
    const int mi  = tid >> 6;
    const int m   = m0 + mi;
    const int rev = (rev_mask >> dir) & 1;
    const float* xw  = dir ? xw1  : xw0;
    const float* Whh = dir ? Whh1 : Whh0;
    const int G4 = 4 * H;
    const size_t BH = (size_t)BSZ * H;

    // stage this block's 16 Whh rows (gate g, cell mi) once
    const int rowq = H >> 2;
    for (int idx = tid; idx < 16 * rowq; idx += 256) {
        const int rr = idx / rowq;
        const int kk = (idx - rr * rowq) << 2;
        const int g = rr >> 2, mm = m0 + (rr & 3);
        const float4 w = *reinterpret_cast<const float4*>(&Whh[(size_t)(g * H + mm) * H + kk]);
        *reinterpret_cast<float4*>(&Whh_s[rr * H + kk]) = w;
    }

    float c  = c0 ? c0[(size_t)b * H + m] : 0.f;
    float hn = h0 ? h0[(size_t)b * H + m] : 0.f;
    hbuf[(size_t)(dir * 2) * BH + (size_t)b * H + m] = hn;   // phase 0 init

    grid_barrier(bar_cnt, bar_gen, nb);

    for (int s = 0; s < T; ++s) {
        const int tt = rev ? (T - 1 - s) : s;
        const float* xwt = xw + ((size_t)tt * BSZ + b) * G4 + m;
        const float xg0 = xwt[0];
        const float xg1 = xwt[H];
        const float xg2 = xwt[2 * H];
        const float xg3 = xwt[3 * H];
        float a0 = 0.f, a1 = 0.f, a2 = 0.f, a3 = 0.f;

        const float* hr = hbuf + (size_t)(dir * 2 + (s & 1)) * BH;
        float* hw       = hbuf + (size_t)(dir * 2 + ((s + 1) & 1)) * BH;

        for (int k0 = 0; k0 < H; k0 += 64) {
            __syncthreads();
#pragma unroll
            for (int q = 0; q < 4; ++q) {
                const int idx = tid + q * 256;
                const int rr = idx >> 4;
                const int kk = (idx & 15) << 2;
                const float4 h4 = *reinterpret_cast<const float4*>(&hr[(size_t)rr * H + k0 + kk]);
                ht[rr][kk + 0] = h4.x; ht[rr][kk + 1] = h4.y;
                ht[rr][kk + 2] = h4.z; ht[rr][kk + 3] = h4.w;
            }
            __syncthreads();
            const float* w0p = &Whh_s[(0  + mi) * H + k0];
            const float* w1p = &Whh_s[(4  + mi) * H + k0];
            const float* w2p = &Whh_s[(8  + mi) * H + k0];
            const float* w3p = &Whh_s[(12 + mi) * H + k0];
#pragma unroll
            for (int k = 0; k < 64; k += 4) {
                const float4 w0 = *reinterpret_cast<const float4*>(&w0p[k]);
                const float4 w1 = *reinterpret_cast<const float4*>(&w1p[k]);
                const float4 w2 = *reinterpret_cast<const float4*>(&w2p[k]);
                const float4 w3 = *reinterpret_cast<const float4*>(&w3p[k]);
                const float h0v = ht[b][k + 0];
                const float h1v = ht[b][k + 1];
                const float h2v = ht[b][k + 2];
                const float h3v = ht[b][k + 3];
                a0 += w0.x * h0v + w0.y * h1v + w0.z * h2v + w0.w * h3v;
                a1 += w1.x * h0v + w1.y * h1v + w1.z * h2v + w1.w * h3v;
                a2 += w2.x * h0v + w2.y * h1v + w2.z * h2v + w2.w * h3v;
                a3 += w3.x * h0v + w3.y * h1v + w3.z * h2v + w3.w * h3v;
            }
        }
        const float ig = sigmoidf_(a0 + xg0);
        const float fg = sigmoidf_(a1 + xg1);
        const float gg = tanhf(a2 + xg2);
        const float og = sigmoidf_(a3 + xg3);
        c  = fg * c + ig * gg;
        hn = og * tanhf(c);
        hw[(size_t)b * H + m] = hn;
        if (y_out) y_out[((size_t)tt * BSZ + b) * y_stride + dir * H + m] = hn;
        grid_barrier(bar_cnt, bar_gen, nb);
    }

    if (hs_dst) hs_dst[(size_t)b * DHID_ + dir * H + m] = hn;
    if (cs_dst) cs_dst[(size_t)b * DHID_ + dir * H + m] = c;
}

// ---------------- in-place row log-softmax ----------------
__global__ __launch_bounds__(256) void logsoftmax_kernel(float* __restrict__ x, int cols)
{
    const int tid = threadIdx.x;
    float* p = x + (size_t)blockIdx.x * cols;
    float m = -3.0e38f, s = 0.f;
    for (int cc = tid; cc < cols; cc += 256) {
        const float v = p[cc];
        if (v > m) { s = s * expf(m - v) + 1.f; m = v; }
        else       { s += expf(v - m); }
    }
    __shared__ float ms[256], ss[256];
    ms[tid] = m; ss[tid] = s;
    __syncthreads();
    for (int off = 128; off > 0; off >>= 1) {
        if (tid < off) {
            const float m2 = ms[tid + off], s2 = ss[tid + off];
            const float m1 = ms[tid],       s1 = ss[tid];
            const float M = fmaxf(m1, m2);
            ss[tid] = s1 * expf(m1 - M) + s2 * expf(m2 - M);
            ms[tid] = M;
        }
        __syncthreads();
    }
    const float M = ms[0];
    const float L = logf(ss[0]);
    for (int cc = tid; cc < cols; cc += 256) p[cc] = p[cc] - M - L;
}

// ---------------- host-side orchestration ----------------
extern "C" void kernel_launch(void* const* d_in, const int* in_sizes, int n_in,
                              void* d_out, int out_size, void* d_ws, size_t ws_size,
                              hipStream_t stream)
{
    const int*   sent  = (const int*)d_in[0];
    const int*   targ  = (const int*)d_in[1];
    const float* emb   = (const float*)d_in[2];
    const float* e0Wih = (const float*)d_in[3];
    const float* e0Whh = (const float*)d_in[4];
    const float* e0bih = (const float*)d_in[5];
    const float* e0bhh = (const float*)d_in[6];
    const float* e1Wih = (const float*)d_in[7];
    const float* e1Whh = (const float*)d_in[8];
    const float* e1bih = (const float*)d_in[9];
    const float* e1bhh = (const float*)d_in[10];
    const float* d0Wih = (const float*)d_in[11];
    const float* d0Whh = (const float*)d_in[12];
    const float* d0bih = (const float*)d_in[13];
    const float* d0bhh = (const float*)d_in[14];
    const float* d1Wih = (const float*)d_in[15];
    const float* d1Whh = (const float*)d_in[16];
    const float* d1bih = (const float*)d_in[17];
    const float* d1bhh = (const float*)d_in[18];
    const float* Wout  = (const float*)d_in[19];
    const float* bout  = (const float*)d_in[20];

    float* ws   = (float*)d_ws;
    float* x0   = ws + WS_X0;
    float* xcat = ws + WS_XCAT;
    float* xwA  = ws + WS_XWA;
    float* xwB  = ws + WS_XWB;
    float* hbuf = ws + WS_HBUF;
    float* hs   = ws + WS_HS;
    float* cs   = ws + WS_CS;
    int*   bar  = (int*)(ws + WS_BAR);
    float* out  = (float*)d_out;
    float* decy0 = xcat;                                   // (T,B,1024)
    float* decy1 = xcat + (size_t)T_LEN * BSZ * DHID_;     // (T,B,1024)

    hipMemsetAsync(bar, 0, 64, stream);

    // ---- encoder layer 0 ----
    embed_src_kernel<<<S_LEN * BSZ, 64, 0, stream>>>(sent, emb, x0);
    {
        dim3 g(2048 / 64, (S_LEN * BSZ) / 64);
        gemm_bias_kernel<<<g, 256, 0, stream>>>(x0, e0Wih,              e0bih,        e0bhh,        xwA,
                                                S_LEN * BSZ, 4 * HID_, EMBD);
        gemm_bias_kernel<<<g, 256, 0, stream>>>(x0, e0Wih + 2048 * 256, e0bih + 2048, e0bhh + 2048, xwB,
                                                S_LEN * BSZ, 4 * HID_, EMBD);
    }
    lstm_scan_kernel<<<256, 256, 0, stream>>>(xwA, xwB, e0Whh, e0Whh + 2048 * 512, hbuf,
                                              nullptr, nullptr, xcat, 2 * HID_,
                                              hs, cs, S_LEN, HID_, 2, 2, bar, bar + 1);
    // ---- encoder layer 1 (y discarded; only final states needed) ----
    {
        dim3 g(2048 / 64, (S_LEN * BSZ) / 64);
        gemm_bias_kernel<<<g, 256, 0, stream>>>(xcat, e1Wih,               e1bih,        e1bhh,        xwA,
                                                S_LEN * BSZ, 4 * HID_, 2 * HID_);
        gemm_bias_kernel<<<g, 256, 0, stream>>>(xcat, e1Wih + 2048 * 1024, e1bih + 2048, e1bhh + 2048, xwB,
                                                S_LEN * BSZ, 4 * HID_, 2 * HID_);
    }
    lstm_scan_kernel<<<256, 256, 0, stream>>>(xwA, xwB, e1Whh, e1Whh + 2048 * 512, hbuf,
                                              nullptr, nullptr, nullptr, 0,
                                              hs + BSZ * DHID_, cs + BSZ * DHID_,
                                              S_LEN, HID_, 2, 2, bar, bar + 1);
    // ---- decoder ----
    embed_dec_kernel<<<T_LEN * BSZ, 64, 0, stream>>>(sent, targ, emb, x0);
    {
        dim3 g(4096 / 64, (T_LEN * BSZ) / 64);
        gemm_bias_kernel<<<g, 256, 0, stream>>>(x0, d0Wih, d0bih, d0bhh, xwA,
                                                T_LEN * BSZ, 4 * DHID_, EMBD);
    }
    lstm_scan_kernel<<<256, 256, 0, stream>>>(xwA, nullptr, d0Whh, nullptr, hbuf,
                                              hs, cs, decy0, DHID_,
                                              nullptr, nullptr, T_LEN, DHID_, 1, 0, bar, bar + 1);
    {
        dim3 g(4096 / 64, (T_LEN * BSZ) / 64);
        gemm_bias_kernel<<<g, 256, 0, stream>>>(decy0, d1Wih, d1bih, d1bhh, xwB,
                                                T_LEN * BSZ, 4 * DHID_, DHID_);
    }
    lstm_scan_kernel<<<256, 256, 0, stream>>>(xwB, nullptr, d1Whh, nullptr, hbuf,
                                              hs + BSZ * DHID_, cs + BSZ * DHID_, decy1, DHID_,
                                              nullptr, nullptr, T_LEN, DHID_, 1, 0, bar, bar + 1);
    // ---- vocab projection + log-softmax ----
    {
        dim3 g(VOC_ / 64, (T_LEN * BSZ) / 64);
        gemm_bias_kernel<<<g, 256, 0, stream>>>(decy1, Wout, bout, nullptr, out,
                                                T_LEN * BSZ, VOC_, DHID_);
    }
    logsoftmax_kernel<<<T_LEN * BSZ, 256, 0, stream>>>(out, VOC_);
}

// Round 2
// 13763.965 us; speedup vs baseline: 3.1035x; 3.1035x over previous
//
#include <hip/hip_runtime.h>

#define S_LEN 128
#define T_LEN 64
#define BSZ   64
#define EMBD  256
#define HID_  512
#define DHID_ 1024
#define VOC_  32000
#define HSTR  1024   // row stride (floats) of every h-history / state buffer

typedef float f4_t __attribute__((ext_vector_type(4)));

// ---------------- workspace layout (float offsets) ----------------
#define WS_X0   0ull
#define WS_XCAT (WS_X0   + (size_t)S_LEN * BSZ * EMBD)        //  2,097,152
#define WS_XWA  (WS_XCAT + (size_t)S_LEN * BSZ * (2 * HID_))  // 10,485,760
#define WS_XWB  (WS_XWA  + (size_t)S_LEN * BSZ * (4 * HID_))  // 27,262,976
#define WS_HS   (WS_XWB  + (size_t)S_LEN * BSZ * (4 * HID_))  // 44,040,192
#define WS_CS   (WS_HS   + (size_t)2 * BSZ * DHID_)
#define WS_BAR  (WS_CS   + (size_t)2 * BSZ * DHID_)

// ---------------- coherent (LLC-scope) memory helpers ----------------
__device__ __forceinline__ f4_t sc_load4(const float* p) {
    f4_t v;
    asm volatile("global_load_dwordx4 %0, %1, off sc0 sc1" : "=v"(v) : "v"(p));
    return v;                                   // NOT ready until wait_vm0()
}
__device__ __forceinline__ void sc_store1(float* p, float v) {
    asm volatile("global_store_dword %0, %1, off sc0 sc1" :: "v"(p), "v"(v) : "memory");
}
__device__ __forceinline__ void wait_vm0() {
    asm volatile("s_waitcnt vmcnt(0)" ::: "memory");
    __builtin_amdgcn_sched_barrier(0);
}

// ---------------- embedding gathers ----------------
__global__ __launch_bounds__(64) void embed_src_kernel(
    const int* __restrict__ toks, const float* __restrict__ emb,
    float* __restrict__ out)
{
    const int i = blockIdx.x;
    const int tok = toks[i];
    const float4* src = reinterpret_cast<const float4*>(emb + (size_t)tok * EMBD);
    float4* dst = reinterpret_cast<float4*>(out + (size_t)i * EMBD);
    dst[threadIdx.x] = src[threadIdx.x];
}

__global__ __launch_bounds__(64) void embed_dec_kernel(
    const int* __restrict__ sent, const int* __restrict__ targ,
    const float* __restrict__ emb, float* __restrict__ out)
{
    const int i = blockIdx.x;
    const int t = i >> 6, b = i & 63;
    const int tok = (t == 0) ? sent[(S_LEN - 1) * BSZ + b] : targ[(t - 1) * BSZ + b];
    const float4* src = reinterpret_cast<const float4*>(emb + (size_t)tok * EMBD);
    float4* dst = reinterpret_cast<float4*>(out + (size_t)i * EMBD);
    dst[threadIdx.x] = src[threadIdx.x];
}

// ---------------- fp32 GEMM:  C[M,N] = A[M,K] * B[N,K]^T + b1[N] (+ b2[N]) ----------------
__global__ __launch_bounds__(256) void gemm_bias_kernel(
    const float* __restrict__ A, const float* __restrict__ B,
    const float* __restrict__ b1, const float* __restrict__ b2,
    float* __restrict__ C, int M, int N, int K)
{
    __shared__ __align__(16) float As[16][64];
    __shared__ __align__(16) float Bs[16][64];
    const int tid = threadIdx.x;
    const int bn = blockIdx.x * 64;
    const int bm = blockIdx.y * 64;
    const int tx = tid & 15;
    const int ty = tid >> 4;
    const int r  = tid >> 2;
    const int kq = (tid & 3) << 2;

    float acc[4][4] = {{0.f,0.f,0.f,0.f},{0.f,0.f,0.f,0.f},
                       {0.f,0.f,0.f,0.f},{0.f,0.f,0.f,0.f}};

    for (int k0 = 0; k0 < K; k0 += 16) {
        const float4 a4 = *reinterpret_cast<const float4*>(&A[(size_t)(bm + r) * K + k0 + kq]);
        const float4 b4 = *reinterpret_cast<const float4*>(&B[(size_t)(bn + r) * K + k0 + kq]);
        __syncthreads();
        As[kq + 0][r] = a4.x; As[kq + 1][r] = a4.y; As[kq + 2][r] = a4.z; As[kq + 3][r] = a4.w;
        Bs[kq + 0][r] = b4.x; Bs[kq + 1][r] = b4.y; Bs[kq + 2][r] = b4.z; Bs[kq + 3][r] = b4.w;
        __syncthreads();
#pragma unroll
        for (int k = 0; k < 16; ++k) {
            const float4 av = *reinterpret_cast<const float4*>(&As[k][ty << 2]);
            const float4 bv = *reinterpret_cast<const float4*>(&Bs[k][tx << 2]);
            const float a0 = av.x, a1 = av.y, a2 = av.z, a3 = av.w;
            const float c0 = bv.x, c1 = bv.y, c2 = bv.z, c3 = bv.w;
            acc[0][0] += a0 * c0; acc[0][1] += a0 * c1; acc[0][2] += a0 * c2; acc[0][3] += a0 * c3;
            acc[1][0] += a1 * c0; acc[1][1] += a1 * c1; acc[1][2] += a1 * c2; acc[1][3] += a1 * c3;
            acc[2][0] += a2 * c0; acc[2][1] += a2 * c1; acc[2][2] += a2 * c2; acc[2][3] += a2 * c3;
            acc[3][0] += a3 * c0; acc[3][1] += a3 * c1; acc[3][2] += a3 * c2; acc[3][3] += a3 * c3;
        }
    }
#pragma unroll
    for (int i = 0; i < 4; ++i) {
        const int row = bm + (ty << 2) + i;
#pragma unroll
        for (int j = 0; j < 4; ++j) {
            const int col = bn + (tx << 2) + j;
            float v = acc[i][j] + b1[col];
            if (b2) v += b2[col];
            C[(size_t)row * N + col] = v;
        }
    }
}

// ---------------- grid barrier: relaxed LLC atomics, one release per step ----------------
// Caller must wait_vm0() first so every wave's sc-stores are LLC-visible.
__device__ __forceinline__ void grid_barrier(int* cnt, int* gen, int nb)
{
    __syncthreads();
    if (threadIdx.x == 0) {
        const int g = __hip_atomic_load(gen, __ATOMIC_RELAXED, __HIP_MEMORY_SCOPE_AGENT);
        const int t = __hip_atomic_fetch_add(cnt, 1, __ATOMIC_RELAXED, __HIP_MEMORY_SCOPE_AGENT);
        if (t == nb - 1) {
            __hip_atomic_store(cnt, 0, __ATOMIC_RELAXED, __HIP_MEMORY_SCOPE_AGENT);
            __hip_atomic_fetch_add(gen, 1, __ATOMIC_RELEASE, __HIP_MEMORY_SCOPE_AGENT);
        } else {
            while (__hip_atomic_load(gen, __ATOMIC_RELAXED, __HIP_MEMORY_SCOPE_AGENT) == g)
                __builtin_amdgcn_s_sleep(1);
        }
    }
    __syncthreads();
}

__device__ __forceinline__ float sigmoidf_(float x) { return 1.f / (1.f + expf(-x)); }

// ---------------- persistent LSTM scan, t-indexed h history ----------------
// Grid: 256 blocks x 256 threads; ndir*H == 1024. hist: (T,B,HSTR), col offset dir*H —
// serves as BOTH y output and h history. h0/c0 optional (B,HSTR) init, col dir*H.
// All hist/h0 traffic is sc0sc1 (LLC-coherent); xw/Whh are plain cached loads.
__global__ __launch_bounds__(256, 1) void lstm_scan_kernel(
    const float* __restrict__ xw0, const float* __restrict__ xw1,
    const float* __restrict__ Whh0, const float* __restrict__ Whh1,
    const float* __restrict__ h0, const float* __restrict__ c0,
    float* __restrict__ hist,
    float* __restrict__ hs_dst, float* __restrict__ cs_dst,
    int T, int H, int ndir, int rev_mask, int* bar)
{
    __shared__ __align__(16) float Whh_s[16 * DHID_];   // 64 KB
    __shared__ float ht[64][65];                        // 16.6 KB  -> 1 block/CU

    const int tid = threadIdx.x;
    const int bpd = gridDim.x / ndir;
    const int dir = blockIdx.x / bpd;
    const int blk = blockIdx.x - dir * bpd;
    const int m0  = blk * 4;
    const int b   = tid & 63;
    const int mi  = tid >> 6;
    const int m   = m0 + mi;
    const int rev = (rev_mask >> dir) & 1;
    const float* xw  = dir ? xw1  : xw0;
    const float* Whh = dir ? Whh1 : Whh0;
    int* cnt = bar + dir * 64;
    int* gen = cnt + 32;
    const int colofs = dir * H;
    const int G4 = 4 * H;
    const int ntiles = H >> 6;

    // stage this block's 16 Whh rows (4 gates x 4 cells)
    const int rowq = H >> 2;
    for (int idx = tid; idx < 16 * rowq; idx += 256) {
        const int rr = idx / rowq;
        const int kk = (idx - rr * rowq) << 2;
        const int g = rr >> 2, mm = m0 + (rr & 3);
        *reinterpret_cast<f4_t*>(&Whh_s[rr * H + kk]) =
            *reinterpret_cast<const f4_t*>(&Whh[(size_t)(g * H + mm) * H + kk]);
    }
    __syncthreads();

    float c  = c0 ? c0[(size_t)b * HSTR + colofs + m] : 0.f;
    float hn = 0.f;

    const int rr_s = tid >> 4;            // staging row within 16-row group
    const int kk_s = (tid & 15) << 2;     // staging col quad

    for (int s = 0; s < T; ++s) {
        const int tt = rev ? (T - 1 - s) : s;
        const float* hp;
        if (s == 0) hp = h0;                                  // may be null (zeros)
        else {
            const int tp = rev ? (tt + 1) : (tt - 1);
            hp = hist + (size_t)tp * (BSZ * HSTR);
        }
        const float* xwt = xw + ((size_t)tt * BSZ + b) * G4 + m;
        const float xg0 = xwt[0];
        const float xg1 = xwt[H];
        const float xg2 = xwt[2 * H];
        const float xg3 = xwt[3 * H];
        float a0 = 0.f, a1 = 0.f, a2 = 0.f, a3 = 0.f;

        if (hp) {
            const float* base = hp + colofs + kk_s;
            // prologue: issue tile 0 loads
            f4_t r0 = sc_load4(base + (size_t)(rr_s +  0) * HSTR);
            f4_t r1 = sc_load4(base + (size_t)(rr_s + 16) * HSTR);
            f4_t r2 = sc_load4(base + (size_t)(rr_s + 32) * HSTR);
            f4_t r3 = sc_load4(base + (size_t)(rr_s + 48) * HSTR);
            for (int kt = 0; kt < ntiles; ++kt) {
                __syncthreads();                 // ht free (prev tile's compute done)
                wait_vm0();                      // loads for this tile complete
                ht[rr_s +  0][kk_s+0]=r0.x; ht[rr_s +  0][kk_s+1]=r0.y; ht[rr_s +  0][kk_s+2]=r0.z; ht[rr_s +  0][kk_s+3]=r0.w;
                ht[rr_s + 16][kk_s+0]=r1.x; ht[rr_s + 16][kk_s+1]=r1.y; ht[rr_s + 16][kk_s+2]=r1.z; ht[rr_s + 16][kk_s+3]=r1.w;
                ht[rr_s + 32][kk_s+0]=r2.x; ht[rr_s + 32][kk_s+1]=r2.y; ht[rr_s + 32][kk_s+2]=r2.z; ht[rr_s + 32][kk_s+3]=r2.w;
                ht[rr_s + 48][kk_s+0]=r3.x; ht[rr_s + 48][kk_s+1]=r3.y; ht[rr_s + 48][kk_s+2]=r3.z; ht[rr_s + 48][kk_s+3]=r3.w;
                __syncthreads();                 // ht ready
                if (kt + 1 < ntiles) {           // overlap next tile's loads with compute
                    const float* nb2 = base + ((kt + 1) << 6);
                    r0 = sc_load4(nb2 + (size_t)(rr_s +  0) * HSTR);
                    r1 = sc_load4(nb2 + (size_t)(rr_s + 16) * HSTR);
                    r2 = sc_load4(nb2 + (size_t)(rr_s + 32) * HSTR);
                    r3 = sc_load4(nb2 + (size_t)(rr_s + 48) * HSTR);
                }
                const int k0 = kt << 6;
                const float* w0p = &Whh_s[(0  + mi) * H + k0];
                const float* w1p = &Whh_s[(4  + mi) * H + k0];
                const float* w2p = &Whh_s[(8  + mi) * H + k0];
                const float* w3p = &Whh_s[(12 + mi) * H + k0];
#pragma unroll
                for (int k = 0; k < 64; k += 4) {
                    const f4_t w0 = *reinterpret_cast<const f4_t*>(&w0p[k]);
                    const f4_t w1 = *reinterpret_cast<const f4_t*>(&w1p[k]);
                    const f4_t w2 = *reinterpret_cast<const f4_t*>(&w2p[k]);
                    const f4_t w3 = *reinterpret_cast<const f4_t*>(&w3p[k]);
                    const float h0v = ht[b][k + 0];
                    const float h1v = ht[b][k + 1];
                    const float h2v = ht[b][k + 2];
                    const float h3v = ht[b][k + 3];
                    a0 += w0.x * h0v + w0.y * h1v + w0.z * h2v + w0.w * h3v;
                    a1 += w1.x * h0v + w1.y * h1v + w1.z * h2v + w1.w * h3v;
                    a2 += w2.x * h0v + w2.y * h1v + w2.z * h2v + w2.w * h3v;
                    a3 += w3.x * h0v + w3.y * h1v + w3.z * h2v + w3.w * h3v;
                }
            }
        }
        const float ig = sigmoidf_(a0 + xg0);
        const float fg = sigmoidf_(a1 + xg1);
        const float gg = tanhf(a2 + xg2);
        const float og = sigmoidf_(a3 + xg3);
        c  = fg * c + ig * gg;
        hn = og * tanhf(c);
        sc_store1(&hist[(size_t)tt * (BSZ * HSTR) + (size_t)b * HSTR + colofs + m], hn);
        wait_vm0();                              // h visible at LLC before arrive
        if (s + 1 < T) grid_barrier(cnt, gen, bpd);
    }

    if (hs_dst) hs_dst[(size_t)b * HSTR + colofs + m] = hn;
    if (cs_dst) cs_dst[(size_t)b * HSTR + colofs + m] = c;
}

// ---------------- in-place row log-softmax ----------------
__global__ __launch_bounds__(256) void logsoftmax_kernel(float* __restrict__ x, int cols)
{
    const int tid = threadIdx.x;
    float* p = x + (size_t)blockIdx.x * cols;
    float m = -3.0e38f, s = 0.f;
    for (int cc = tid; cc < cols; cc += 256) {
        const float v = p[cc];
        if (v > m) { s = s * expf(m - v) + 1.f; m = v; }
        else       { s += expf(v - m); }
    }
    __shared__ float ms[256], ss[256];
    ms[tid] = m; ss[tid] = s;
    __syncthreads();
    for (int off = 128; off > 0; off >>= 1) {
        if (tid < off) {
            const float m2 = ms[tid + off], s2 = ss[tid + off];
            const float m1 = ms[tid],       s1 = ss[tid];
            const float M = fmaxf(m1, m2);
            ss[tid] = s1 * expf(m1 - M) + s2 * expf(m2 - M);
            ms[tid] = M;
        }
        __syncthreads();
    }
    const float M = ms[0];
    const float L = logf(ss[0]);
    for (int cc = tid; cc < cols; cc += 256) p[cc] = p[cc] - M - L;
}

// ---------------- host-side orchestration ----------------
extern "C" void kernel_launch(void* const* d_in, const int* in_sizes, int n_in,
                              void* d_out, int out_size, void* d_ws, size_t ws_size,
                              hipStream_t stream)
{
    const int*   sent  = (const int*)d_in[0];
    const int*   targ  = (const int*)d_in[1];
    const float* emb   = (const float*)d_in[2];
    const float* e0Wih = (const float*)d_in[3];
    const float* e0Whh = (const float*)d_in[4];
    const float* e0bih = (const float*)d_in[5];
    const float* e0bhh = (const float*)d_in[6];
    const float* e1Wih = (const float*)d_in[7];
    const float* e1Whh = (const float*)d_in[8];
    const float* e1bih = (const float*)d_in[9];
    const float* e1bhh = (const float*)d_in[10];
    const float* d0Wih = (const float*)d_in[11];
    const float* d0Whh = (const float*)d_in[12];
    const float* d0bih = (const float*)d_in[13];
    const float* d0bhh = (const float*)d_in[14];
    const float* d1Wih = (const float*)d_in[15];
    const float* d1Whh = (const float*)d_in[16];
    const float* d1bih = (const float*)d_in[17];
    const float* d1bhh = (const float*)d_in[18];
    const float* Wout  = (const float*)d_in[19];
    const float* bout  = (const float*)d_in[20];

    float* ws   = (float*)d_ws;
    float* x0   = ws + WS_X0;
    float* xcat = ws + WS_XCAT;
    float* xwA  = ws + WS_XWA;
    float* xwB  = ws + WS_XWB;
    float* hs   = ws + WS_HS;
    float* cs   = ws + WS_CS;
    int*   bar  = (int*)(ws + WS_BAR);
    float* out  = (float*)d_out;
    float* hist1 = (float*)d_out;                          // enc layer-1 h history scratch
    float* decy0 = xcat;                                   // (T,B,1024)
    float* decy1 = xcat + (size_t)T_LEN * BSZ * DHID_;     // (T,B,1024)

    hipMemsetAsync(bar, 0, 512, stream);

    // ---- encoder layer 0 ----
    embed_src_kernel<<<S_LEN * BSZ, 64, 0, stream>>>(sent, emb, x0);
    {
        dim3 g(2048 / 64, (S_LEN * BSZ) / 64);
        gemm_bias_kernel<<<g, 256, 0, stream>>>(x0, e0Wih,              e0bih,        e0bhh,        xwA,
                                                S_LEN * BSZ, 4 * HID_, EMBD);
        gemm_bias_kernel<<<g, 256, 0, stream>>>(x0, e0Wih + 2048 * 256, e0bih + 2048, e0bhh + 2048, xwB,
                                                S_LEN * BSZ, 4 * HID_, EMBD);
    }
    lstm_scan_kernel<<<256, 256, 0, stream>>>(xwA, xwB, e0Whh, e0Whh + 2048 * 512,
                                              nullptr, nullptr, xcat,
                                              hs, cs, S_LEN, HID_, 2, 2, bar);
    // ---- encoder layer 1 (y only needed as its own h history -> d_out scratch) ----
    {
        dim3 g(2048 / 64, (S_LEN * BSZ) / 64);
        gemm_bias_kernel<<<g, 256, 0, stream>>>(xcat, e1Wih,               e1bih,        e1bhh,        xwA,
                                                S_LEN * BSZ, 4 * HID_, 2 * HID_);
        gemm_bias_kernel<<<g, 256, 0, stream>>>(xcat, e1Wih + 2048 * 1024, e1bih + 2048, e1bhh + 2048, xwB,
                                                S_LEN * BSZ, 4 * HID_, 2 * HID_);
    }
    lstm_scan_kernel<<<256, 256, 0, stream>>>(xwA, xwB, e1Whh, e1Whh + 2048 * 512,
                                              nullptr, nullptr, hist1,
                                              hs + BSZ * DHID_, cs + BSZ * DHID_,
                                              S_LEN, HID_, 2, 2, bar);
    // ---- decoder ----
    embed_dec_kernel<<<T_LEN * BSZ, 64, 0, stream>>>(sent, targ, emb, x0);
    {
        dim3 g(4096 / 64, (T_LEN * BSZ) / 64);
        gemm_bias_kernel<<<g, 256, 0, stream>>>(x0, d0Wih, d0bih, d0bhh, xwA,
                                                T_LEN * BSZ, 4 * DHID_, EMBD);
    }
    lstm_scan_kernel<<<256, 256, 0, stream>>>(xwA, nullptr, d0Whh, nullptr,
                                              hs, cs, decy0,
                                              nullptr, nullptr, T_LEN, DHID_, 1, 0, bar);
    {
        dim3 g(4096 / 64, (T_LEN * BSZ) / 64);
        gemm_bias_kernel<<<g, 256, 0, stream>>>(decy0, d1Wih, d1bih, d1bhh, xwB,
                                                T_LEN * BSZ, 4 * DHID_, DHID_);
    }
    lstm_scan_kernel<<<256, 256, 0, stream>>>(xwB, nullptr, d1Whh, nullptr,
                                              hs + BSZ * DHID_, cs + BSZ * DHID_, decy1,
                                              nullptr, nullptr, T_LEN, DHID_, 1, 0, bar);
    // ---- vocab projection + log-softmax ----
    {
        dim3 g(VOC_ / 64, (T_LEN * BSZ) / 64);
        gemm_bias_kernel<<<g, 256, 0, stream>>>(decy1, Wout, bout, nullptr, out,
                                                T_LEN * BSZ, VOC_, DHID_);
    }
    logsoftmax_kernel<<<T_LEN * BSZ, 256, 0, stream>>>(out, VOC_);
}

// Round 3
// 8998.922 us; speedup vs baseline: 4.7468x; 1.5295x over previous
//
#include <hip/hip_runtime.h>

#define S_LEN 128
#define T_LEN 64
#define BSZ   64
#define EMBD  256
#define HID_  512
#define DHID_ 1024
#define VOC_  32000
#define HSTR  1024   // row stride (floats/elems) of h-history & state buffers

typedef float  f4_t  __attribute__((ext_vector_type(4)));
typedef float  f32x4 __attribute__((ext_vector_type(4)));
typedef short  s16x8 __attribute__((ext_vector_type(8)));
typedef __bf16 bf16x8 __attribute__((ext_vector_type(8)));
typedef unsigned short u16x4 __attribute__((ext_vector_type(4)));

// ---------------- workspace layout (float offsets) ----------------
#define WS_HIST 0ull                                   // 8,388,608  (fp32 h history, shared by all scans)
#define WS_XWA  (WS_HIST + 8388608ull)                 // 16,777,216
#define WS_XWB  (WS_XWA  + 16777216ull)                // 16,777,216
#define WS_HS   (WS_XWB  + 16777216ull)                // 131,072
#define WS_CS   (WS_HS   + 131072ull)                  // 131,072
#define WS_BAR  (WS_CS   + 131072ull)                  // 128
#define WS_BF   (WS_BAR  + 128ull)                     // bf16 region below (ushort units)
// ushort offsets inside bf16 region:
#define U_X0B   0ull                                   // 2,097,152  (embedded tokens bf16)
#define U_XCATB (U_X0B   + 2097152ull)                 // 8,388,608  (enc0 y bf16; later decy0b/decy1b)
#define U_E0W   (U_XCATB + 8388608ull)                 // 1,048,576
#define U_E1W   (U_E0W   + 1048576ull)                 // 4,194,304
#define U_D0W   (U_E1W   + 4194304ull)                 // 1,048,576
#define U_D1W   (U_D0W   + 1048576ull)                 // 4,194,304

__device__ __forceinline__ unsigned short f2bf(float x) {
    unsigned u = __builtin_bit_cast(unsigned, x);
    return (unsigned short)((u + 0x7fffu + ((u >> 16) & 1u)) >> 16);
}

// ---------------- coherent (LLC-scope) memory helpers ----------------
__device__ __forceinline__ f4_t sc_load4(const float* p) {
    f4_t v;
    asm volatile("global_load_dwordx4 %0, %1, off sc0 sc1" : "=v"(v) : "v"(p));
    return v;                                   // NOT ready until wait_vm0()
}
__device__ __forceinline__ void sc_store1(float* p, float v) {
    asm volatile("global_store_dword %0, %1, off sc0 sc1" :: "v"(p), "v"(v) : "memory");
}
__device__ __forceinline__ void wait_vm0() {
    asm volatile("s_waitcnt vmcnt(0)" ::: "memory");
    __builtin_amdgcn_sched_barrier(0);
}

__device__ __forceinline__ void gload_lds16(const void* g, void* l) {
    __builtin_amdgcn_global_load_lds(
        (const __attribute__((address_space(1))) void*)g,
        (__attribute__((address_space(3))) void*)l, 16, 0, 0);
}

// ---------------- fp32 -> bf16 conversion ----------------
__global__ __launch_bounds__(256) void f2b_kernel(
    const float* __restrict__ in, unsigned short* __restrict__ out, int n4)
{
    const int stride = gridDim.x * 256;
    for (int i = blockIdx.x * 256 + threadIdx.x; i < n4; i += stride) {
        const float4 v = reinterpret_cast<const float4*>(in)[i];
        u16x4 o = { f2bf(v.x), f2bf(v.y), f2bf(v.z), f2bf(v.w) };
        reinterpret_cast<u16x4*>(out)[i] = o;
    }
}

// ---------------- embedding gathers (emit bf16) ----------------
__global__ __launch_bounds__(64) void embed_src_kernel(
    const int* __restrict__ toks, const float* __restrict__ emb,
    unsigned short* __restrict__ out)
{
    const int i = blockIdx.x;
    const int tok = toks[i];
    const float4 v = reinterpret_cast<const float4*>(emb + (size_t)tok * EMBD)[threadIdx.x];
    u16x4 o = { f2bf(v.x), f2bf(v.y), f2bf(v.z), f2bf(v.w) };
    reinterpret_cast<u16x4*>(out + (size_t)i * EMBD)[threadIdx.x] = o;
}

__global__ __launch_bounds__(64) void embed_dec_kernel(
    const int* __restrict__ sent, const int* __restrict__ targ,
    const float* __restrict__ emb, unsigned short* __restrict__ out)
{
    const int i = blockIdx.x;
    const int t = i >> 6, b = i & 63;
    const int tok = (t == 0) ? sent[(S_LEN - 1) * BSZ + b] : targ[(t - 1) * BSZ + b];
    const float4 v = reinterpret_cast<const float4*>(emb + (size_t)tok * EMBD)[threadIdx.x];
    u16x4 o = { f2bf(v.x), f2bf(v.y), f2bf(v.z), f2bf(v.w) };
    reinterpret_cast<u16x4*>(out + (size_t)i * EMBD)[threadIdx.x] = o;
}

// ---------------- bf16 MFMA GEMM:  C[M,N] = A[M,K] * B[N,K]^T + b1[N] (+ b2[N]) ----------------
// M,N multiples of 128; K multiple of 64. 256 threads = 4 waves (2x2 of 64x64).
// T2 swizzle: LDS rows are 128B (64 bf16); 16B-chunk c of row r holds global chunk c^(r&7);
// achieved by pre-swizzling the global source (linear global_load_lds dest) per guide m201/m173.
__global__ __launch_bounds__(256) void gemm_bf16_kernel(
    const unsigned short* __restrict__ A, const unsigned short* __restrict__ B,
    const float* __restrict__ b1, const float* __restrict__ b2,
    float* __restrict__ C, int M, int N, int K, int nTN)
{
    __shared__ __align__(16) unsigned short As[128 * 64];
    __shared__ __align__(16) unsigned short Bs[128 * 64];

    const int tid  = threadIdx.x;
    const int lane = tid & 63;
    const int wv   = tid >> 6;
    const int wm   = wv >> 1, wn = wv & 1;

    // bijective XCD-aware swizzle (m204): consecutive work on an XCD shares the same M-row panel
    const int nwg = gridDim.x;
    const int q = nwg >> 3, r = nwg & 7;
    const int xcd = blockIdx.x & 7, io = blockIdx.x >> 3;
    const int wg = (xcd < r ? xcd * (q + 1) : r * (q + 1) + (xcd - r) * q) + io;
    const int bm = (wg / nTN) * 128;
    const int bn = (wg % nTN) * 128;

    f32x4 acc[4][4];
#pragma unroll
    for (int i = 0; i < 4; ++i)
#pragma unroll
        for (int j = 0; j < 4; ++j) acc[i][j] = (f32x4)0.f;

    const int lin_base = wv * 1024 + lane * 16;

    for (int k0 = 0; k0 < K; k0 += 64) {
        __syncthreads();
#pragma unroll
        for (int qc = 0; qc < 4; ++qc) {
            const int lin = qc * 4096 + lin_base;      // linear byte pos in 16KB tile
            const int row = lin >> 7;                  // 128B rows
            const int c   = (lin >> 4) & 7;            // 16B chunk within row
            const int sc  = c ^ (row & 7);             // pre-swizzled source chunk
            const size_t gofs = (size_t)(bm + row) * K + k0 + sc * 8;
            const size_t gofsB = (size_t)(bn + row) * K + k0 + sc * 8;
            char* ldst = (char*)As + qc * 4096 + wv * 1024;   // wave-uniform
            char* ldstB = (char*)Bs + qc * 4096 + wv * 1024;
            gload_lds16(A + gofs, ldst);
            gload_lds16(B + gofsB, ldstB);
        }
        asm volatile("s_waitcnt vmcnt(0)" ::: "memory");
        __syncthreads();
#pragma unroll
        for (int ks = 0; ks < 2; ++ks) {
            bf16x8 af[4], bfv[4];
            const int ca = ks * 4 + (lane >> 4);
#pragma unroll
            for (int f = 0; f < 4; ++f) {
                const int ra = wm * 64 + f * 16 + (lane & 15);
                af[f] = __builtin_bit_cast(bf16x8,
                    *(const s16x8*)((const char*)As + ra * 128 + ((ca ^ (ra & 7)) << 4)));
                const int rb = wn * 64 + f * 16 + (lane & 15);
                bfv[f] = __builtin_bit_cast(bf16x8,
                    *(const s16x8*)((const char*)Bs + rb * 128 + ((ca ^ (rb & 7)) << 4)));
            }
#pragma unroll
            for (int i = 0; i < 4; ++i)
#pragma unroll
                for (int j = 0; j < 4; ++j)
                    acc[i][j] = __builtin_amdgcn_mfma_f32_16x16x32_bf16(
                        af[i], bfv[j], acc[i][j], 0, 0, 0);
        }
    }

    // epilogue: C/D layout col=lane&15, row=(lane>>4)*4+reg (verified m89/m91)
    const int col0 = bn + wn * 64 + (lane & 15);
    const int row0 = bm + wm * 64 + ((lane >> 4) << 2);
#pragma unroll
    for (int i = 0; i < 4; ++i) {
#pragma unroll
        for (int j = 0; j < 4; ++j) {
            const int col = col0 + j * 16;
            float bias = b1[col];
            if (b2) bias += b2[col];
#pragma unroll
            for (int rg = 0; rg < 4; ++rg) {
                C[(size_t)(row0 + i * 16 + rg) * N + col] = acc[i][j][rg] + bias;
            }
        }
    }
}

// ---------------- grid barrier: relaxed LLC atomics, one release per step ----------------
__device__ __forceinline__ void grid_barrier(int* cnt, int* gen, int nb)
{
    __syncthreads();
    if (threadIdx.x == 0) {
        const int g = __hip_atomic_load(gen, __ATOMIC_RELAXED, __HIP_MEMORY_SCOPE_AGENT);
        const int t = __hip_atomic_fetch_add(cnt, 1, __ATOMIC_RELAXED, __HIP_MEMORY_SCOPE_AGENT);
        if (t == nb - 1) {
            __hip_atomic_store(cnt, 0, __ATOMIC_RELAXED, __HIP_MEMORY_SCOPE_AGENT);
            __hip_atomic_fetch_add(gen, 1, __ATOMIC_RELEASE, __HIP_MEMORY_SCOPE_AGENT);
        } else {
            while (__hip_atomic_load(gen, __ATOMIC_RELAXED, __HIP_MEMORY_SCOPE_AGENT) == g)
                __builtin_amdgcn_s_sleep(1);
        }
    }
    __syncthreads();
}

__device__ __forceinline__ float sigmoidf_(float x) { return 1.f / (1.f + expf(-x)); }

// ---------------- persistent LSTM scan, t-indexed h history ----------------
// Grid: 256 blocks x 256 threads; ndir*H == 1024. hist: (T,B,HSTR) fp32 — y AND h history.
// yb (optional): bf16 y copy, same (T,B,HSTR) geometry, for downstream MFMA GEMMs.
__global__ __launch_bounds__(256, 1) void lstm_scan_kernel(
    const float* __restrict__ xw0, const float* __restrict__ xw1,
    const float* __restrict__ Whh0, const float* __restrict__ Whh1,
    const float* __restrict__ h0, const float* __restrict__ c0,
    float* __restrict__ hist, unsigned short* __restrict__ yb,
    float* __restrict__ hs_dst, float* __restrict__ cs_dst,
    int T, int H, int ndir, int rev_mask, int* bar)
{
    __shared__ __align__(16) float Whh_s[16 * DHID_];   // 64 KB
    __shared__ float ht[64][65];                        // 16.6 KB  -> 1 block/CU

    const int tid = threadIdx.x;
    const int bpd = gridDim.x / ndir;
    const int dir = blockIdx.x / bpd;
    const int blk = blockIdx.x - dir * bpd;
    const int m0  = blk * 4;
    const int b   = tid & 63;
    const int mi  = tid >> 6;
    const int m   = m0 + mi;
    const int rev = (rev_mask >> dir) & 1;
    const float* xw  = dir ? xw1  : xw0;
    const float* Whh = dir ? Whh1 : Whh0;
    int* cnt = bar + dir * 64;
    int* gen = cnt + 32;
    const int colofs = dir * H;
    const int G4 = 4 * H;
    const int ntiles = H >> 6;

    // stage this block's 16 Whh rows (4 gates x 4 cells)
    const int rowq = H >> 2;
    for (int idx = tid; idx < 16 * rowq; idx += 256) {
        const int rr = idx / rowq;
        const int kk = (idx - rr * rowq) << 2;
        const int g = rr >> 2, mm = m0 + (rr & 3);
        *reinterpret_cast<f4_t*>(&Whh_s[rr * H + kk]) =
            *reinterpret_cast<const f4_t*>(&Whh[(size_t)(g * H + mm) * H + kk]);
    }
    __syncthreads();

    float c  = c0 ? c0[(size_t)b * HSTR + colofs + m] : 0.f;
    float hn = 0.f;

    const int rr_s = tid >> 4;            // staging row within 16-row group
    const int kk_s = (tid & 15) << 2;     // staging col quad

    for (int s = 0; s < T; ++s) {
        const int tt = rev ? (T - 1 - s) : s;
        const float* hp;
        if (s == 0) hp = h0;                                  // may be null (zeros)
        else {
            const int tp = rev ? (tt + 1) : (tt - 1);
            hp = hist + (size_t)tp * (BSZ * HSTR);
        }
        const float* xwt = xw + ((size_t)tt * BSZ + b) * G4 + m;
        const float xg0 = xwt[0];
        const float xg1 = xwt[H];
        const float xg2 = xwt[2 * H];
        const float xg3 = xwt[3 * H];
        float a0 = 0.f, a1 = 0.f, a2 = 0.f, a3 = 0.f;

        if (hp) {
            const float* base = hp + colofs + kk_s;
            f4_t r0 = sc_load4(base + (size_t)(rr_s +  0) * HSTR);
            f4_t r1 = sc_load4(base + (size_t)(rr_s + 16) * HSTR);
            f4_t r2 = sc_load4(base + (size_t)(rr_s + 32) * HSTR);
            f4_t r3 = sc_load4(base + (size_t)(rr_s + 48) * HSTR);
            for (int kt = 0; kt < ntiles; ++kt) {
                __syncthreads();                 // ht free (prev tile's compute done)
                wait_vm0();                      // loads for this tile complete
                ht[rr_s +  0][kk_s+0]=r0.x; ht[rr_s +  0][kk_s+1]=r0.y; ht[rr_s +  0][kk_s+2]=r0.z; ht[rr_s +  0][kk_s+3]=r0.w;
                ht[rr_s + 16][kk_s+0]=r1.x; ht[rr_s + 16][kk_s+1]=r1.y; ht[rr_s + 16][kk_s+2]=r1.z; ht[rr_s + 16][kk_s+3]=r1.w;
                ht[rr_s + 32][kk_s+0]=r2.x; ht[rr_s + 32][kk_s+1]=r2.y; ht[rr_s + 32][kk_s+2]=r2.z; ht[rr_s + 32][kk_s+3]=r2.w;
                ht[rr_s + 48][kk_s+0]=r3.x; ht[rr_s + 48][kk_s+1]=r3.y; ht[rr_s + 48][kk_s+2]=r3.z; ht[rr_s + 48][kk_s+3]=r3.w;
                __syncthreads();                 // ht ready
                if (kt + 1 < ntiles) {           // overlap next tile's loads with compute
                    const float* nb2 = base + ((kt + 1) << 6);
                    r0 = sc_load4(nb2 + (size_t)(rr_s +  0) * HSTR);
                    r1 = sc_load4(nb2 + (size_t)(rr_s + 16) * HSTR);
                    r2 = sc_load4(nb2 + (size_t)(rr_s + 32) * HSTR);
                    r3 = sc_load4(nb2 + (size_t)(rr_s + 48) * HSTR);
                }
                const int k0 = kt << 6;
                const float* w0p = &Whh_s[(0  + mi) * H + k0];
                const float* w1p = &Whh_s[(4  + mi) * H + k0];
                const float* w2p = &Whh_s[(8  + mi) * H + k0];
                const float* w3p = &Whh_s[(12 + mi) * H + k0];
#pragma unroll
                for (int k = 0; k < 64; k += 4) {
                    const f4_t w0 = *reinterpret_cast<const f4_t*>(&w0p[k]);
                    const f4_t w1 = *reinterpret_cast<const f4_t*>(&w1p[k]);
                    const f4_t w2 = *reinterpret_cast<const f4_t*>(&w2p[k]);
                    const f4_t w3 = *reinterpret_cast<const f4_t*>(&w3p[k]);
                    const float h0v = ht[b][k + 0];
                    const float h1v = ht[b][k + 1];
                    const float h2v = ht[b][k + 2];
                    const float h3v = ht[b][k + 3];
                    a0 += w0.x * h0v + w0.y * h1v + w0.z * h2v + w0.w * h3v;
                    a1 += w1.x * h0v + w1.y * h1v + w1.z * h2v + w1.w * h3v;
                    a2 += w2.x * h0v + w2.y * h1v + w2.z * h2v + w2.w * h3v;
                    a3 += w3.x * h0v + w3.y * h1v + w3.z * h2v + w3.w * h3v;
                }
            }
        }
        const float ig = sigmoidf_(a0 + xg0);
        const float fg = sigmoidf_(a1 + xg1);
        const float gg = tanhf(a2 + xg2);
        const float og = sigmoidf_(a3 + xg3);
        c  = fg * c + ig * gg;
        hn = og * tanhf(c);
        sc_store1(&hist[(size_t)tt * (BSZ * HSTR) + (size_t)b * HSTR + colofs + m], hn);
        if (yb) yb[(size_t)tt * (BSZ * HSTR) + (size_t)b * HSTR + colofs + m] = f2bf(hn);
        wait_vm0();                              // h visible at LLC before arrive
        if (s + 1 < T) grid_barrier(cnt, gen, bpd);
    }

    if (hs_dst) hs_dst[(size_t)b * HSTR + colofs + m] = hn;
    if (cs_dst) cs_dst[(size_t)b * HSTR + colofs + m] = c;
}

// ---------------- in-place row log-softmax (float4) ----------------
__global__ __launch_bounds__(256) void logsoftmax_kernel(float* __restrict__ x, int n4)
{
    const int tid = threadIdx.x;
    float4* p = reinterpret_cast<float4*>(x + (size_t)blockIdx.x * (n4 * 4));
    float m = -3.0e38f, s = 0.f;
    for (int cc = tid; cc < n4; cc += 256) {
        const float4 v = p[cc];
        const float vv[4] = { v.x, v.y, v.z, v.w };
#pragma unroll
        for (int e = 0; e < 4; ++e) {
            const float z = vv[e];
            if (z > m) { s = s * expf(m - z) + 1.f; m = z; }
            else       { s += expf(z - m); }
        }
    }
    __shared__ float ms[256], ss[256];
    ms[tid] = m; ss[tid] = s;
    __syncthreads();
    for (int off = 128; off > 0; off >>= 1) {
        if (tid < off) {
            const float m2 = ms[tid + off], s2 = ss[tid + off];
            const float m1 = ms[tid],       s1 = ss[tid];
            const float M = fmaxf(m1, m2);
            ss[tid] = s1 * expf(m1 - M) + s2 * expf(m2 - M);
            ms[tid] = M;
        }
        __syncthreads();
    }
    const float ML = ms[0] + logf(ss[0]);
    for (int cc = tid; cc < n4; cc += 256) {
        float4 v = p[cc];
        v.x -= ML; v.y -= ML; v.z -= ML; v.w -= ML;
        p[cc] = v;
    }
}

// ---------------- host-side orchestration ----------------
extern "C" void kernel_launch(void* const* d_in, const int* in_sizes, int n_in,
                              void* d_out, int out_size, void* d_ws, size_t ws_size,
                              hipStream_t stream)
{
    const int*   sent  = (const int*)d_in[0];
    const int*   targ  = (const int*)d_in[1];
    const float* emb   = (const float*)d_in[2];
    const float* e0Wih = (const float*)d_in[3];
    const float* e0Whh = (const float*)d_in[4];
    const float* e0bih = (const float*)d_in[5];
    const float* e0bhh = (const float*)d_in[6];
    const float* e1Wih = (const float*)d_in[7];
    const float* e1Whh = (const float*)d_in[8];
    const float* e1bih = (const float*)d_in[9];
    const float* e1bhh = (const float*)d_in[10];
    const float* d0Wih = (const float*)d_in[11];
    const float* d0Whh = (const float*)d_in[12];
    const float* d0bih = (const float*)d_in[13];
    const float* d0bhh = (const float*)d_in[14];
    const float* d1Wih = (const float*)d_in[15];
    const float* d1Whh = (const float*)d_in[16];
    const float* d1bih = (const float*)d_in[17];
    const float* d1bhh = (const float*)d_in[18];
    const float* Wout  = (const float*)d_in[19];
    const float* bout  = (const float*)d_in[20];

    float* ws   = (float*)d_ws;
    float* hist = ws + WS_HIST;
    float* xwA  = ws + WS_XWA;
    float* xwB  = ws + WS_XWB;
    float* hs   = ws + WS_HS;
    float* cs   = ws + WS_CS;
    int*   bar  = (int*)(ws + WS_BAR);
    unsigned short* ub     = (unsigned short*)(ws + WS_BF);
    unsigned short* x0b    = ub + U_X0B;
    unsigned short* xcatb  = ub + U_XCATB;
    unsigned short* decy0b = xcatb;                        // reuse after enc1 proj
    unsigned short* decy1b = xcatb + 4194304ull;
    unsigned short* e0Wb   = ub + U_E0W;
    unsigned short* e1Wb   = ub + U_E1W;
    unsigned short* d0Wb   = ub + U_D0W;
    unsigned short* d1Wb   = ub + U_D1W;
    unsigned short* Woutb  = (unsigned short*)xwA;         // reuse xwA after dec0 scan
    float* out  = (float*)d_out;

    hipMemsetAsync(bar, 0, 512, stream);

    // ---- weight conversions (fp32 -> bf16) ----
    f2b_kernel<<<256, 256, 0, stream>>>(e0Wih, e0Wb, 1048576 / 4);
    f2b_kernel<<<512, 256, 0, stream>>>(e1Wih, e1Wb, 4194304 / 4);
    f2b_kernel<<<256, 256, 0, stream>>>(d0Wih, d0Wb, 1048576 / 4);
    f2b_kernel<<<512, 256, 0, stream>>>(d1Wih, d1Wb, 4194304 / 4);

    // ---- encoder layer 0 ----
    embed_src_kernel<<<S_LEN * BSZ, 64, 0, stream>>>(sent, emb, x0b);
    gemm_bf16_kernel<<<64 * 16, 256, 0, stream>>>(x0b, e0Wb, e0bih, e0bhh, xwA,
                                                  S_LEN * BSZ, 2048, EMBD, 16);
    gemm_bf16_kernel<<<64 * 16, 256, 0, stream>>>(x0b, e0Wb + 2048ull * 256, e0bih + 2048, e0bhh + 2048, xwB,
                                                  S_LEN * BSZ, 2048, EMBD, 16);
    lstm_scan_kernel<<<256, 256, 0, stream>>>(xwA, xwB, e0Whh, e0Whh + 2048ull * 512,
                                              nullptr, nullptr, hist, xcatb,
                                              hs, cs, S_LEN, HID_, 2, 2, bar);
    // ---- encoder layer 1 (only final states needed) ----
    gemm_bf16_kernel<<<64 * 16, 256, 0, stream>>>(xcatb, e1Wb, e1bih, e1bhh, xwA,
                                                  S_LEN * BSZ, 2048, 2 * HID_, 16);
    gemm_bf16_kernel<<<64 * 16, 256, 0, stream>>>(xcatb, e1Wb + 2048ull * 1024, e1bih + 2048, e1bhh + 2048, xwB,
                                                  S_LEN * BSZ, 2048, 2 * HID_, 16);
    lstm_scan_kernel<<<256, 256, 0, stream>>>(xwA, xwB, e1Whh, e1Whh + 2048ull * 512,
                                              nullptr, nullptr, hist, nullptr,
                                              hs + BSZ * DHID_, cs + BSZ * DHID_,
                                              S_LEN, HID_, 2, 2, bar);
    // ---- decoder layer 0 ----
    embed_dec_kernel<<<T_LEN * BSZ, 64, 0, stream>>>(sent, targ, emb, x0b);
    gemm_bf16_kernel<<<32 * 32, 256, 0, stream>>>(x0b, d0Wb, d0bih, d0bhh, xwA,
                                                  T_LEN * BSZ, 4 * DHID_, EMBD, 32);
    lstm_scan_kernel<<<256, 256, 0, stream>>>(xwA, nullptr, d0Whh, nullptr,
                                              hs, cs, hist, decy0b,
                                              nullptr, nullptr, T_LEN, DHID_, 1, 0, bar);
    // ---- Wout -> bf16 (xwA region is free now) ----
    f2b_kernel<<<2048, 256, 0, stream>>>(Wout, Woutb, (VOC_ * DHID_) / 4);
    // ---- decoder layer 1 ----
    gemm_bf16_kernel<<<32 * 32, 256, 0, stream>>>(decy0b, d1Wb, d1bih, d1bhh, xwB,
                                                  T_LEN * BSZ, 4 * DHID_, DHID_, 32);
    lstm_scan_kernel<<<256, 256, 0, stream>>>(xwB, nullptr, d1Whh, nullptr,
                                              hs + BSZ * DHID_, cs + BSZ * DHID_, hist, decy1b,
                                              nullptr, nullptr, T_LEN, DHID_, 1, 0, bar);
    // ---- vocab projection + log-softmax ----
    gemm_bf16_kernel<<<32 * 250, 256, 0, stream>>>(decy1b, Woutb, bout, nullptr, out,
                                                   T_LEN * BSZ, VOC_, DHID_, 250);
    logsoftmax_kernel<<<T_LEN * BSZ, 256, 0, stream>>>(out, VOC_ / 4);
}

// Round 4
// 3767.337 us; speedup vs baseline: 11.3385x; 2.3887x over previous
//
#include <hip/hip_runtime.h>

#define S_LEN 128
#define T_LEN 64
#define BSZ   64
#define EMBD  256
#define HID_  512
#define DHID_ 1024
#define VOC_  32000
#define HSTR  1024

typedef float  f4_t  __attribute__((ext_vector_type(4)));
typedef float  f32x4 __attribute__((ext_vector_type(4)));
typedef short  s16x8 __attribute__((ext_vector_type(8)));
typedef __bf16 bf16x8 __attribute__((ext_vector_type(8)));
typedef unsigned short u16x4 __attribute__((ext_vector_type(4)));

// ---------------- workspace layout ----------------
// float offsets:
#define WS_XWA  0ull                       // 16,777,216 fl (dec0 xw / enc xw dir0; later Wout bf16)
#define WS_XWB  (WS_XWA + 16777216ull)     // 16,777,216 fl
#define WS_CS   (WS_XWB + 16777216ull)     // 131,072 fl (2 layers x (B,HSTR) fp32 c-state)
#define WS_BAR  (WS_CS  + 131072ull)       // 18,432 ints (4 barrier regions x 4608)
#define WS_BF   (WS_BAR + 18432ull)
// ushort offsets within bf16 region:
#define U_X0B   0ull                       // 2,097,152   embedded tokens bf16
#define U_HE0   (U_X0B + 2097152ull)       // 8,388,608   enc0 h history / y (S,B,1024)
#define U_HE1   (U_HE0 + 8388608ull)       // 8,388,608   enc1 h history
#define U_HD0   (U_HE1 + 8388608ull)       // 4,194,304   dec0 h history / y (T,B,1024)
#define U_HD1   (U_HD0 + 4194304ull)       // 4,194,304   dec1 h history / y
#define U_HSB   (U_HD1 + 4194304ull)       // 131,072     final h bf16, 2 layers x (B,1024)
#define U_E0W   (U_HSB + 131072ull)        // 1,048,576
#define U_E1W   (U_E0W + 1048576ull)       // 4,194,304
#define U_D0W   (U_E1W + 4194304ull)       // 1,048,576
#define U_D1W   (U_D0W + 1048576ull)       // 4,194,304

__device__ __forceinline__ unsigned short f2bf(float x) {
    unsigned u = __builtin_bit_cast(unsigned, x);
    return (unsigned short)((u + 0x7fffu + ((u >> 16) & 1u)) >> 16);
}

// ---------------- coherent (LLC-scope) memory helpers ----------------
__device__ __forceinline__ f4_t sc_load4(const void* p) {
    f4_t v;
    asm volatile("global_load_dwordx4 %0, %1, off sc0 sc1" : "=v"(v) : "v"(p));
    return v;                               // NOT ready until a vmcnt wait
}
__device__ __forceinline__ int sc_load1(const int* p) {
    int v;
    asm volatile("global_load_dword %0, %1, off sc0 sc1\n\ts_waitcnt vmcnt(0)"
                 : "=v"(v) : "v"(p) : "memory");
    return v;
}
__device__ __forceinline__ void sc_store_int(int* p, int v) {
    asm volatile("global_store_dword %0, %1, off sc0 sc1" :: "v"(p), "v"(v) : "memory");
}
__device__ __forceinline__ void sc_store_short(unsigned short* p, unsigned v) {
    asm volatile("global_store_short %0, %1, off sc0 sc1" :: "v"(p), "v"(v) : "memory");
}
__device__ __forceinline__ float g_load1(const float* p) {   // plain cached load, no wait
    float v;
    asm volatile("global_load_dword %0, %1, off" : "=v"(v) : "v"(p));
    return v;
}
__device__ __forceinline__ void wait_vm0() {
    asm volatile("s_waitcnt vmcnt(0)" ::: "memory");
}
__device__ __forceinline__ void wait_vm8() {
    asm volatile("s_waitcnt vmcnt(8)" ::: "memory");
}

__device__ __forceinline__ void gload_lds16(const void* g, void* l) {
    __builtin_amdgcn_global_load_lds(
        (const __attribute__((address_space(1))) void*)g,
        (__attribute__((address_space(3))) void*)l, 16, 0, 0);
}

__device__ __forceinline__ float sigmoidf_(float x) { return 1.f / (1.f + expf(-x)); }

// ---------------- fp32 -> bf16 conversion ----------------
__global__ __launch_bounds__(256) void f2b_kernel(
    const float* __restrict__ in, unsigned short* __restrict__ out, int n4)
{
    const int stride = gridDim.x * 256;
    for (int i = blockIdx.x * 256 + threadIdx.x; i < n4; i += stride) {
        const float4 v = reinterpret_cast<const float4*>(in)[i];
        u16x4 o = { f2bf(v.x), f2bf(v.y), f2bf(v.z), f2bf(v.w) };
        reinterpret_cast<u16x4*>(out)[i] = o;
    }
}

// ---------------- embedding gathers (emit bf16) ----------------
__global__ __launch_bounds__(64) void embed_src_kernel(
    const int* __restrict__ toks, const float* __restrict__ emb,
    unsigned short* __restrict__ out)
{
    const int i = blockIdx.x;
    const int tok = toks[i];
    const float4 v = reinterpret_cast<const float4*>(emb + (size_t)tok * EMBD)[threadIdx.x];
    u16x4 o = { f2bf(v.x), f2bf(v.y), f2bf(v.z), f2bf(v.w) };
    reinterpret_cast<u16x4*>(out + (size_t)i * EMBD)[threadIdx.x] = o;
}

__global__ __launch_bounds__(64) void embed_dec_kernel(
    const int* __restrict__ sent, const int* __restrict__ targ,
    const float* __restrict__ emb, unsigned short* __restrict__ out)
{
    const int i = blockIdx.x;
    const int t = i >> 6, b = i & 63;
    const int tok = (t == 0) ? sent[(S_LEN - 1) * BSZ + b] : targ[(t - 1) * BSZ + b];
    const float4 v = reinterpret_cast<const float4*>(emb + (size_t)tok * EMBD)[threadIdx.x];
    u16x4 o = { f2bf(v.x), f2bf(v.y), f2bf(v.z), f2bf(v.w) };
    reinterpret_cast<u16x4*>(out + (size_t)i * EMBD)[threadIdx.x] = o;
}

// ---------------- bf16 MFMA GEMM:  C[M,N] = A[M,K] * B[N,K]^T + b1[N] (+ b2[N]) ----------------
__global__ __launch_bounds__(256) void gemm_bf16_kernel(
    const unsigned short* __restrict__ A, const unsigned short* __restrict__ B,
    const float* __restrict__ b1, const float* __restrict__ b2,
    float* __restrict__ C, int M, int N, int K, int nTN)
{
    __shared__ __align__(16) unsigned short As[128 * 64];
    __shared__ __align__(16) unsigned short Bs[128 * 64];

    const int tid  = threadIdx.x;
    const int lane = tid & 63;
    const int wv   = tid >> 6;
    const int wm   = wv >> 1, wn = wv & 1;

    const int nwg = gridDim.x;
    const int q = nwg >> 3, r = nwg & 7;
    const int xcd = blockIdx.x & 7, io = blockIdx.x >> 3;
    const int wg = (xcd < r ? xcd * (q + 1) : r * (q + 1) + (xcd - r) * q) + io;
    const int bm = (wg / nTN) * 128;
    const int bn = (wg % nTN) * 128;

    f32x4 acc[4][4];
#pragma unroll
    for (int i = 0; i < 4; ++i)
#pragma unroll
        for (int j = 0; j < 4; ++j) acc[i][j] = (f32x4)0.f;

    const int lin_base = wv * 1024 + lane * 16;

    for (int k0 = 0; k0 < K; k0 += 64) {
        __syncthreads();
#pragma unroll
        for (int qc = 0; qc < 4; ++qc) {
            const int lin = qc * 4096 + lin_base;
            const int row = lin >> 7;
            const int c   = (lin >> 4) & 7;
            const int sc  = c ^ (row & 7);
            const size_t gofs  = (size_t)(bm + row) * K + k0 + sc * 8;
            const size_t gofsB = (size_t)(bn + row) * K + k0 + sc * 8;
            char* ldst  = (char*)As + qc * 4096 + wv * 1024;
            char* ldstB = (char*)Bs + qc * 4096 + wv * 1024;
            gload_lds16(A + gofs, ldst);
            gload_lds16(B + gofsB, ldstB);
        }
        asm volatile("s_waitcnt vmcnt(0)" ::: "memory");
        __syncthreads();
#pragma unroll
        for (int ks = 0; ks < 2; ++ks) {
            bf16x8 af[4], bfv[4];
            const int ca = ks * 4 + (lane >> 4);
#pragma unroll
            for (int f = 0; f < 4; ++f) {
                const int ra = wm * 64 + f * 16 + (lane & 15);
                af[f] = __builtin_bit_cast(bf16x8,
                    *(const s16x8*)((const char*)As + ra * 128 + ((ca ^ (ra & 7)) << 4)));
                const int rb = wn * 64 + f * 16 + (lane & 15);
                bfv[f] = __builtin_bit_cast(bf16x8,
                    *(const s16x8*)((const char*)Bs + rb * 128 + ((ca ^ (rb & 7)) << 4)));
            }
#pragma unroll
            for (int i = 0; i < 4; ++i)
#pragma unroll
                for (int j = 0; j < 4; ++j)
                    acc[i][j] = __builtin_amdgcn_mfma_f32_16x16x32_bf16(
                        af[i], bfv[j], acc[i][j], 0, 0, 0);
        }
    }

    const int col0 = bn + wn * 64 + (lane & 15);
    const int row0 = bm + wm * 64 + ((lane >> 4) << 2);
#pragma unroll
    for (int i = 0; i < 4; ++i) {
#pragma unroll
        for (int j = 0; j < 4; ++j) {
            const int col = col0 + j * 16;
            float bias = b1[col];
            if (b2) bias += b2[col];
#pragma unroll
            for (int rg = 0; rg < 4; ++rg) {
                C[(size_t)(row0 + i * 16 + rg) * N + col] = acc[i][j][rg] + bias;
            }
        }
    }
}

// ---------------- persistent MFMA LSTM scan ----------------
// Grid 256x256. ndir*(H_T/4)/... : 4 cells per block; enc: 2 dirs x 128 blocks; dec: 256 blocks.
// hist: (T,B,1024) bf16 — h history AND y output (cols dir*H_T..).
// h0b: (B,1024) bf16 initial h (or null = zeros); c0: (B,HSTR) fp32 (or null).
// Barrier region `bar`: gen[dir] at bar+dir*16; flags at bar+64+blockIdx*16. Must be zeroed.
template<int H_T>
__global__ __launch_bounds__(256, 1) void lstm_mfma_scan(
    const float* __restrict__ xw0, const float* __restrict__ xw1,
    const float* __restrict__ Whh0, const float* __restrict__ Whh1,
    const unsigned short* __restrict__ h0b, const float* __restrict__ c0,
    unsigned short* __restrict__ hist,
    unsigned short* __restrict__ hsb, float* __restrict__ csd,
    int T, int ndir, int rev_mask, int* bar)
{
    constexpr int KST = H_T / 32;       // MFMA k-steps
    constexpr int CH  = H_T / 8;        // 16B chunks per h row
    constexpr int NB  = CH / 32;        // staging batches of 8 per thread (2 enc / 4 dec)

    __shared__ __align__(16) unsigned short h_lds[64 * H_T];  // 64KB / 128KB
    __shared__ float pre[64][17];

    const int tid  = threadIdx.x;
    const int lane = tid & 63;
    const int w    = tid >> 6;          // wave = M-quarter (batch rows w*16..w*16+15)
    const int bpd  = (ndir == 2) ? 128 : 256;
    const int dir  = blockIdx.x / bpd;
    const int blk  = blockIdx.x - dir * bpd;
    const int m0   = blk * 4;
    const int rev  = (rev_mask >> dir) & 1;
    const float* xw  = dir ? xw1  : xw0;
    const float* Whh = dir ? Whh1 : Whh0;
    const int dcol = dir * H_T;
    const int b = tid & 63;             // epilogue cell (b, m0+j)
    const int j = tid >> 6;

    int* genp  = bar + dir * 16;
    int* flagp = bar + 64 + blockIdx.x * 16;

    // ---- B-fragments: Whh rows in registers, bf16 ----
    const int n  = lane & 15;           // MFMA col: (gate,cell) = (n>>2, n&3)
    const int kg = lane >> 4;           // k-subgroup
    const int wr = (n >> 2) * H_T + m0 + (n & 3);
    s16x8 wfr[KST];
#pragma unroll
    for (int ks = 0; ks < KST; ++ks) {
        const float* wp = Whh + (size_t)wr * H_T + ks * 32 + kg * 8;
        const float4 lo = *reinterpret_cast<const float4*>(wp);
        const float4 hi = *reinterpret_cast<const float4*>(wp + 4);
        s16x8 rr;
        rr[0] = (short)f2bf(lo.x); rr[1] = (short)f2bf(lo.y);
        rr[2] = (short)f2bf(lo.z); rr[3] = (short)f2bf(lo.w);
        rr[4] = (short)f2bf(hi.x); rr[5] = (short)f2bf(hi.y);
        rr[6] = (short)f2bf(hi.z); rr[7] = (short)f2bf(hi.w);
        wfr[ks] = rr;
    }

    float c  = c0 ? c0[(size_t)b * HSTR + dcol + m0 + j] : 0.f;
    float hn = 0.f;
    const int rA = w * 16 + n;          // A-frag row (batch)
    const int rAx = rA & 7;

    for (int s = 0; s < T; ++s) {
        const int tt = rev ? (T - 1 - s) : s;

        // xw gate inputs (plain cached loads, issued first, tie-waited before use)
        const float* xb = xw + ((size_t)(tt * 64 + b)) * (4 * H_T) + m0 + j;
        float xg0 = g_load1(xb);
        float xg1 = g_load1(xb + H_T);
        float xg2 = g_load1(xb + 2 * H_T);
        float xg3 = g_load1(xb + 3 * H_T);

        const unsigned short* hb;
        size_t tofs;
        if (s == 0) { hb = h0b; tofs = 0; }
        else {
            const int tp = rev ? (tt + 1) : (tt - 1);
            hb = hist; tofs = (size_t)tp * (64 * 1024);
        }

        float p0 = 0.f, p1 = 0.f, p2 = 0.f, p3 = 0.f;
        if (hb) {
            // ---- stage h tile: sc_load4 -> XOR-swizzled LDS, 2-deep counted pipeline ----
            f4_t bufA[8], bufB[8];
            auto issue = [&](f4_t (&bf)[8], int bt) {
#pragma unroll
                for (int jj = 0; jj < 8; ++jj) {
                    const int idx = (bt * 8 + jj) * 256 + tid;
                    const int rr_ = idx / CH, cc_ = idx % CH;
                    bf[jj] = sc_load4(hb + tofs + (size_t)rr_ * 1024 + dcol + cc_ * 8);
                }
            };
            auto writeb = [&](const f4_t (&bf)[8], int bt) {
#pragma unroll
                for (int jj = 0; jj < 8; ++jj) {
                    const int idx = (bt * 8 + jj) * 256 + tid;
                    const int rr_ = idx / CH, cc_ = idx % CH;
                    const int off = rr_ * (2 * H_T) + ((cc_ ^ (rr_ & 7)) << 4);
                    *(f4_t*)((char*)h_lds + off) = bf[jj];
                }
            };
            issue(bufA, 0);
            if (NB > 1) issue(bufB, 1);
#pragma unroll
            for (int bt = 0; bt < NB; ++bt) {
                if (bt + 1 < NB) wait_vm8(); else wait_vm0();
                if (bt & 1) writeb(bufB, bt); else writeb(bufA, bt);
                if (bt + 2 < NB) { if (bt & 1) issue(bufB, bt + 2); else issue(bufA, bt + 2); }
            }
            __syncthreads();

            // ---- MFMA: D[batch][n] += h[batch][k] * W[wr(n)][k] ----
            f32x4 acc = {0.f, 0.f, 0.f, 0.f};
#pragma unroll
            for (int ks = 0; ks < KST; ++ks) {
                const int cc_ = ks * 4 + kg;
                const int off = rA * (2 * H_T) + ((cc_ ^ rAx) << 4);
                const bf16x8 a = __builtin_bit_cast(bf16x8,
                    *(const s16x8*)((const char*)h_lds + off));
                acc = __builtin_amdgcn_mfma_f32_16x16x32_bf16(
                    a, __builtin_bit_cast(bf16x8, wfr[ks]), acc, 0, 0, 0);
            }
            // ---- exchange D -> (b, gate) layout ----
            __syncthreads();
#pragma unroll
            for (int rg = 0; rg < 4; ++rg)
                pre[w * 16 + kg * 4 + rg][n] = acc[rg];
            __syncthreads();
            p0 = pre[b][0 + j]; p1 = pre[b][4 + j];
            p2 = pre[b][8 + j]; p3 = pre[b][12 + j];
        }

        // ensure xg values have landed
        asm volatile("s_waitcnt vmcnt(0)"
                     : "+v"(xg0), "+v"(xg1), "+v"(xg2), "+v"(xg3) :: "memory");

        const float ig = sigmoidf_(p0 + xg0);
        const float fg = sigmoidf_(p1 + xg1);
        const float gg = tanhf(p2 + xg2);
        const float og = sigmoidf_(p3 + xg3);
        c  = fg * c + ig * gg;
        hn = og * tanhf(c);
        sc_store_short(hist + (size_t)tt * (64 * 1024) + (size_t)b * 1024 + dcol + m0 + j,
                       (unsigned)f2bf(hn));
        wait_vm0();                                   // h visible at LLC

        if (s + 1 < T) {
            const int tgt = s + 1;
            if (tid == 0) sc_store_int(flagp, tgt);   // parallel arrival
            if (blk == 0) {
                const int* fp = bar + 64 + (dir * bpd + tid) * 16;
                int ok = (tid >= bpd) ? 1 : 0;
                for (;;) {
                    if (!ok) ok = (sc_load1(fp) >= tgt) ? 1 : 0;
                    if (__syncthreads_and(ok)) break;
                }
                if (tid == 0) sc_store_int(genp, tgt);
            } else {
                if (tid == 0) {
                    while (sc_load1(genp) < tgt) __builtin_amdgcn_s_sleep(2);
                }
                __syncthreads();
            }
        }
    }

    if (hsb) hsb[(size_t)b * 1024 + dcol + m0 + j] = f2bf(hn);
    if (csd) csd[(size_t)b * HSTR + dcol + m0 + j] = c;
}

// ---------------- in-place row log-softmax (float4) ----------------
__global__ __launch_bounds__(256) void logsoftmax_kernel(float* __restrict__ x, int n4)
{
    const int tid = threadIdx.x;
    float4* p = reinterpret_cast<float4*>(x + (size_t)blockIdx.x * (n4 * 4));
    float m = -3.0e38f, s = 0.f;
    for (int cc = tid; cc < n4; cc += 256) {
        const float4 v = p[cc];
        const float vv[4] = { v.x, v.y, v.z, v.w };
#pragma unroll
        for (int e = 0; e < 4; ++e) {
            const float z = vv[e];
            if (z > m) { s = s * expf(m - z) + 1.f; m = z; }
            else       { s += expf(z - m); }
        }
    }
    __shared__ float ms[256], ss[256];
    ms[tid] = m; ss[tid] = s;
    __syncthreads();
    for (int off = 128; off > 0; off >>= 1) {
        if (tid < off) {
            const float m2 = ms[tid + off], s2 = ss[tid + off];
            const float m1 = ms[tid],       s1 = ss[tid];
            const float M = fmaxf(m1, m2);
            ss[tid] = s1 * expf(m1 - M) + s2 * expf(m2 - M);
            ms[tid] = M;
        }
        __syncthreads();
    }
    const float ML = ms[0] + logf(ss[0]);
    for (int cc = tid; cc < n4; cc += 256) {
        float4 v = p[cc];
        v.x -= ML; v.y -= ML; v.z -= ML; v.w -= ML;
        p[cc] = v;
    }
}

// ---------------- host-side orchestration ----------------
extern "C" void kernel_launch(void* const* d_in, const int* in_sizes, int n_in,
                              void* d_out, int out_size, void* d_ws, size_t ws_size,
                              hipStream_t stream)
{
    const int*   sent  = (const int*)d_in[0];
    const int*   targ  = (const int*)d_in[1];
    const float* emb   = (const float*)d_in[2];
    const float* e0Wih = (const float*)d_in[3];
    const float* e0Whh = (const float*)d_in[4];
    const float* e0bih = (const float*)d_in[5];
    const float* e0bhh = (const float*)d_in[6];
    const float* e1Wih = (const float*)d_in[7];
    const float* e1Whh = (const float*)d_in[8];
    const float* e1bih = (const float*)d_in[9];
    const float* e1bhh = (const float*)d_in[10];
    const float* d0Wih = (const float*)d_in[11];
    const float* d0Whh = (const float*)d_in[12];
    const float* d0bih = (const float*)d_in[13];
    const float* d0bhh = (const float*)d_in[14];
    const float* d1Wih = (const float*)d_in[15];
    const float* d1Whh = (const float*)d_in[16];
    const float* d1bih = (const float*)d_in[17];
    const float* d1bhh = (const float*)d_in[18];
    const float* Wout  = (const float*)d_in[19];
    const float* bout  = (const float*)d_in[20];

    float* ws  = (float*)d_ws;
    float* xwA = ws + WS_XWA;
    float* xwB = ws + WS_XWB;
    float* cs  = ws + WS_CS;
    int*   bar = (int*)(ws + WS_BAR);
    unsigned short* ub    = (unsigned short*)(ws + WS_BF);
    unsigned short* x0b   = ub + U_X0B;
    unsigned short* h_e0  = ub + U_HE0;
    unsigned short* h_e1  = ub + U_HE1;
    unsigned short* h_d0  = ub + U_HD0;
    unsigned short* h_d1  = ub + U_HD1;
    unsigned short* hsb   = ub + U_HSB;
    unsigned short* e0Wb  = ub + U_E0W;
    unsigned short* e1Wb  = ub + U_E1W;
    unsigned short* d0Wb  = ub + U_D0W;
    unsigned short* d1Wb  = ub + U_D1W;
    unsigned short* Woutb = (unsigned short*)xwA;   // reused after dec0 scan
    float* out = (float*)d_out;

    hipMemsetAsync(bar, 0, 4 * 4608 * 4, stream);

    // ---- weight conversions (fp32 -> bf16) ----
    f2b_kernel<<<256, 256, 0, stream>>>(e0Wih, e0Wb, 1048576 / 4);
    f2b_kernel<<<512, 256, 0, stream>>>(e1Wih, e1Wb, 4194304 / 4);
    f2b_kernel<<<256, 256, 0, stream>>>(d0Wih, d0Wb, 1048576 / 4);
    f2b_kernel<<<512, 256, 0, stream>>>(d1Wih, d1Wb, 4194304 / 4);

    // ---- encoder layer 0 ----
    embed_src_kernel<<<S_LEN * BSZ, 64, 0, stream>>>(sent, emb, x0b);
    gemm_bf16_kernel<<<64 * 16, 256, 0, stream>>>(x0b, e0Wb, e0bih, e0bhh, xwA,
                                                  S_LEN * BSZ, 2048, EMBD, 16);
    gemm_bf16_kernel<<<64 * 16, 256, 0, stream>>>(x0b, e0Wb + 2048ull * 256,
                                                  e0bih + 2048, e0bhh + 2048, xwB,
                                                  S_LEN * BSZ, 2048, EMBD, 16);
    lstm_mfma_scan<512><<<256, 256, 0, stream>>>(xwA, xwB, e0Whh, e0Whh + 2048ull * 512,
                                                 nullptr, nullptr, h_e0,
                                                 hsb, cs, S_LEN, 2, 2, bar);
    // ---- encoder layer 1 (y discarded; final states only) ----
    gemm_bf16_kernel<<<64 * 16, 256, 0, stream>>>(h_e0, e1Wb, e1bih, e1bhh, xwA,
                                                  S_LEN * BSZ, 2048, 2 * HID_, 16);
    gemm_bf16_kernel<<<64 * 16, 256, 0, stream>>>(h_e0, e1Wb + 2048ull * 1024,
                                                  e1bih + 2048, e1bhh + 2048, xwB,
                                                  S_LEN * BSZ, 2048, 2 * HID_, 16);
    lstm_mfma_scan<512><<<256, 256, 0, stream>>>(xwA, xwB, e1Whh, e1Whh + 2048ull * 512,
                                                 nullptr, nullptr, h_e1,
                                                 hsb + 65536, cs + 65536,
                                                 S_LEN, 2, 2, bar + 4608);
    // ---- decoder layer 0 ----
    embed_dec_kernel<<<T_LEN * BSZ, 64, 0, stream>>>(sent, targ, emb, x0b);
    gemm_bf16_kernel<<<32 * 32, 256, 0, stream>>>(x0b, d0Wb, d0bih, d0bhh, xwA,
                                                  T_LEN * BSZ, 4 * DHID_, EMBD, 32);
    lstm_mfma_scan<1024><<<256, 256, 0, stream>>>(xwA, nullptr, d0Whh, nullptr,
                                                  hsb, cs, h_d0,
                                                  nullptr, nullptr, T_LEN, 1, 0,
                                                  bar + 2 * 4608);
    // ---- Wout -> bf16 (xwA region free now) ----
    f2b_kernel<<<2048, 256, 0, stream>>>(Wout, Woutb, (VOC_ * DHID_) / 4);
    // ---- decoder layer 1 ----
    gemm_bf16_kernel<<<32 * 32, 256, 0, stream>>>(h_d0, d1Wb, d1bih, d1bhh, xwB,
                                                  T_LEN * BSZ, 4 * DHID_, DHID_, 32);
    lstm_mfma_scan<1024><<<256, 256, 0, stream>>>(xwB, nullptr, d1Whh, nullptr,
                                                  hsb + 65536, cs + 65536, h_d1,
                                                  nullptr, nullptr, T_LEN, 1, 0,
                                                  bar + 3 * 4608);
    // ---- vocab projection + log-softmax ----
    gemm_bf16_kernel<<<32 * 250, 256, 0, stream>>>(h_d1, Woutb, bout, nullptr, out,
                                                   T_LEN * BSZ, VOC_, DHID_, 250);
    logsoftmax_kernel<<<T_LEN * BSZ, 256, 0, stream>>>(out, VOC_ / 4);
}

// Round 5
// 2710.754 us; speedup vs baseline: 15.7580x; 1.3898x over previous
//
#include <hip/hip_runtime.h>

#define S_LEN 128
#define T_LEN 64
#define BSZ   64
#define EMBD  256
#define HID_  512
#define DHID_ 1024
#define VOC_  32000
#define HSTR  1024

typedef float  f4_t  __attribute__((ext_vector_type(4)));
typedef float  f32x4 __attribute__((ext_vector_type(4)));
typedef short  s16x8 __attribute__((ext_vector_type(8)));
typedef __bf16 bf16x8 __attribute__((ext_vector_type(8)));
typedef unsigned short u16x4 __attribute__((ext_vector_type(4)));
typedef int    i32x2 __attribute__((ext_vector_type(2)));

// ---------------- workspace layout ----------------
// float offsets:
#define WS_XWA  0ull                       // 16,777,216 fl
#define WS_XWB  (WS_XWA + 16777216ull)     // 16,777,216 fl
#define WS_CS   (WS_XWB + 16777216ull)     // 131,072 fl
#define WS_BAR  (WS_CS  + 131072ull)       // 32,768 ints (4 regions x 8192)
#define WS_BF   (WS_BAR + 32768ull)
// ushort offsets within bf16 region:
#define U_X0B   0ull
#define U_HE0   (U_X0B + 2097152ull)
#define U_HE1   (U_HE0 + 8388608ull)
#define U_HD0   (U_HE1 + 8388608ull)
#define U_HD1   (U_HD0 + 4194304ull)
#define U_HSB   (U_HD1 + 4194304ull)
#define U_E0W   (U_HSB + 131072ull)
#define U_E1W   (U_E0W + 1048576ull)
#define U_D0W   (U_E1W + 4194304ull)
#define U_D1W   (U_D0W + 1048576ull)

__device__ __forceinline__ unsigned short f2bf(float x) {
    unsigned u = __builtin_bit_cast(unsigned, x);
    return (unsigned short)((u + 0x7fffu + ((u >> 16) & 1u)) >> 16);
}

// ---------------- coherent (LLC-scope) memory helpers ----------------
__device__ __forceinline__ f4_t sc_load4(const void* p) {
    f4_t v;
    asm volatile("global_load_dwordx4 %0, %1, off sc0 sc1" : "=v"(v) : "v"(p));
    return v;                               // NOT ready until a vmcnt wait
}
__device__ __forceinline__ int sc_load1(const int* p) {
    int v;
    asm volatile("global_load_dword %0, %1, off sc0 sc1\n\ts_waitcnt vmcnt(0)"
                 : "=v"(v) : "v"(p) : "memory");
    return v;
}
__device__ __forceinline__ void sc_store_int(int* p, int v) {
    asm volatile("global_store_dword %0, %1, off sc0 sc1" :: "v"(p), "v"(v) : "memory");
}
__device__ __forceinline__ void sc_store8(void* p, i32x2 v) {
    asm volatile("global_store_dwordx2 %0, %1, off sc0 sc1" :: "v"(p), "v"(v) : "memory");
}
__device__ __forceinline__ float g_load1(const float* p) {   // plain cached load, no wait
    float v;
    asm volatile("global_load_dword %0, %1, off" : "=v"(v) : "v"(p));
    return v;
}
__device__ __forceinline__ void wait_vm0() {
    asm volatile("s_waitcnt vmcnt(0)" ::: "memory");
}
__device__ __forceinline__ void wait_vm8() {
    asm volatile("s_waitcnt vmcnt(8)" ::: "memory");
}

__device__ __forceinline__ void gload_lds16(const void* g, void* l) {
    __builtin_amdgcn_global_load_lds(
        (const __attribute__((address_space(1))) void*)g,
        (__attribute__((address_space(3))) void*)l, 16, 0, 0);
}

__device__ __forceinline__ float sigmoidf_(float x) { return 1.f / (1.f + expf(-x)); }

// ---------------- fp32 -> bf16 conversion ----------------
__global__ __launch_bounds__(256) void f2b_kernel(
    const float* __restrict__ in, unsigned short* __restrict__ out, int n4)
{
    const int stride = gridDim.x * 256;
    for (int i = blockIdx.x * 256 + threadIdx.x; i < n4; i += stride) {
        const float4 v = reinterpret_cast<const float4*>(in)[i];
        u16x4 o = { f2bf(v.x), f2bf(v.y), f2bf(v.z), f2bf(v.w) };
        reinterpret_cast<u16x4*>(out)[i] = o;
    }
}

// ---------------- embedding gathers (emit bf16) ----------------
__global__ __launch_bounds__(64) void embed_src_kernel(
    const int* __restrict__ toks, const float* __restrict__ emb,
    unsigned short* __restrict__ out)
{
    const int i = blockIdx.x;
    const int tok = toks[i];
    const float4 v = reinterpret_cast<const float4*>(emb + (size_t)tok * EMBD)[threadIdx.x];
    u16x4 o = { f2bf(v.x), f2bf(v.y), f2bf(v.z), f2bf(v.w) };
    reinterpret_cast<u16x4*>(out + (size_t)i * EMBD)[threadIdx.x] = o;
}

__global__ __launch_bounds__(64) void embed_dec_kernel(
    const int* __restrict__ sent, const int* __restrict__ targ,
    const float* __restrict__ emb, unsigned short* __restrict__ out)
{
    const int i = blockIdx.x;
    const int t = i >> 6, b = i & 63;
    const int tok = (t == 0) ? sent[(S_LEN - 1) * BSZ + b] : targ[(t - 1) * BSZ + b];
    const float4 v = reinterpret_cast<const float4*>(emb + (size_t)tok * EMBD)[threadIdx.x];
    u16x4 o = { f2bf(v.x), f2bf(v.y), f2bf(v.z), f2bf(v.w) };
    reinterpret_cast<u16x4*>(out + (size_t)i * EMBD)[threadIdx.x] = o;
}

// ---------------- bf16 MFMA GEMM:  C = A[M,K] * B[N,K]^T + b1 (+ b2) ----------------
// tmode 0: C row-major (M,N). tmode 1: C as (M/64, N, 64) i.e. (T,4H,B) for the scans.
__global__ __launch_bounds__(256) void gemm_bf16_kernel(
    const unsigned short* __restrict__ A, const unsigned short* __restrict__ B,
    const float* __restrict__ b1, const float* __restrict__ b2,
    float* __restrict__ C, int M, int N, int K, int nTN, int tmode)
{
    __shared__ __align__(16) unsigned short As[128 * 64];
    __shared__ __align__(16) unsigned short Bs[128 * 64];

    const int tid  = threadIdx.x;
    const int lane = tid & 63;
    const int wv   = tid >> 6;
    const int wm   = wv >> 1, wn = wv & 1;

    const int nwg = gridDim.x;
    const int q = nwg >> 3, r = nwg & 7;
    const int xcd = blockIdx.x & 7, io = blockIdx.x >> 3;
    const int wg = (xcd < r ? xcd * (q + 1) : r * (q + 1) + (xcd - r) * q) + io;
    const int bm = (wg / nTN) * 128;
    const int bn = (wg % nTN) * 128;

    f32x4 acc[4][4];
#pragma unroll
    for (int i = 0; i < 4; ++i)
#pragma unroll
        for (int j = 0; j < 4; ++j) acc[i][j] = (f32x4)0.f;

    const int lin_base = wv * 1024 + lane * 16;

    for (int k0 = 0; k0 < K; k0 += 64) {
        __syncthreads();
#pragma unroll
        for (int qc = 0; qc < 4; ++qc) {
            const int lin = qc * 4096 + lin_base;
            const int row = lin >> 7;
            const int c   = (lin >> 4) & 7;
            const int sc  = c ^ (row & 7);
            const size_t gofs  = (size_t)(bm + row) * K + k0 + sc * 8;
            const size_t gofsB = (size_t)(bn + row) * K + k0 + sc * 8;
            char* ldst  = (char*)As + qc * 4096 + wv * 1024;
            char* ldstB = (char*)Bs + qc * 4096 + wv * 1024;
            gload_lds16(A + gofs, ldst);
            gload_lds16(B + gofsB, ldstB);
        }
        asm volatile("s_waitcnt vmcnt(0)" ::: "memory");
        __syncthreads();
#pragma unroll
        for (int ks = 0; ks < 2; ++ks) {
            bf16x8 af[4], bfv[4];
            const int ca = ks * 4 + (lane >> 4);
#pragma unroll
            for (int f = 0; f < 4; ++f) {
                const int ra = wm * 64 + f * 16 + (lane & 15);
                af[f] = __builtin_bit_cast(bf16x8,
                    *(const s16x8*)((const char*)As + ra * 128 + ((ca ^ (ra & 7)) << 4)));
                const int rb = wn * 64 + f * 16 + (lane & 15);
                bfv[f] = __builtin_bit_cast(bf16x8,
                    *(const s16x8*)((const char*)Bs + rb * 128 + ((ca ^ (rb & 7)) << 4)));
            }
#pragma unroll
            for (int i = 0; i < 4; ++i)
#pragma unroll
                for (int j = 0; j < 4; ++j)
                    acc[i][j] = __builtin_amdgcn_mfma_f32_16x16x32_bf16(
                        af[i], bfv[j], acc[i][j], 0, 0, 0);
        }
    }

    const int col0 = bn + wn * 64 + (lane & 15);
    if (tmode == 0) {
        const int row0 = bm + wm * 64 + ((lane >> 4) << 2);
#pragma unroll
        for (int i = 0; i < 4; ++i) {
#pragma unroll
            for (int j = 0; j < 4; ++j) {
                const int col = col0 + j * 16;
                float bias = b1[col];
                if (b2) bias += b2[col];
#pragma unroll
                for (int rg = 0; rg < 4; ++rg)
                    C[(size_t)(row0 + i * 16 + rg) * N + col] = acc[i][j][rg] + bias;
            }
        }
    } else {
        // (row>>6, col, row&63); acc's 4 regs are 4 consecutive rows -> one float4
        const int tblk = (bm >> 6) + wm;
        const int rb = (lane >> 4) << 2;
#pragma unroll
        for (int i = 0; i < 4; ++i) {
#pragma unroll
            for (int j = 0; j < 4; ++j) {
                const int col = col0 + j * 16;
                float bias = b1[col];
                if (b2) bias += b2[col];
                float4 v = { acc[i][j][0] + bias, acc[i][j][1] + bias,
                             acc[i][j][2] + bias, acc[i][j][3] + bias };
                *reinterpret_cast<float4*>(&C[((size_t)tblk * N + col) * 64 + rb + i * 16]) = v;
            }
        }
    }
}

// ---------------- persistent MFMA LSTM scan, single-hop flag sync ----------------
// Grid 256x256. hist: (T,B,1024) bf16. xw layout: (T, 4*H_T, B) per dir (transposed).
// Flags: bar + blockIdx.x*32; producer stores s+1 after its h stores drained;
// every block polls all bpd producer flags of its dir directly (no gen hop).
template<int H_T>
__global__ __launch_bounds__(256, 1) void lstm_mfma_scan(
    const float* __restrict__ xw0, const float* __restrict__ xw1,
    const float* __restrict__ Whh0, const float* __restrict__ Whh1,
    const unsigned short* __restrict__ h0b, const float* __restrict__ c0,
    unsigned short* __restrict__ hist,
    unsigned short* __restrict__ hsb, float* __restrict__ csd,
    int T, int ndir, int rev_mask, int* bar)
{
    constexpr int KST = H_T / 32;
    constexpr int CH  = H_T / 8;
    constexpr int NB  = CH / 32;

    __shared__ __align__(16) unsigned short h_lds[64 * H_T];
    __shared__ float pre[64][17];
    __shared__ __align__(8) unsigned short hpack[64][4];

    const int tid  = threadIdx.x;
    const int lane = tid & 63;
    const int w    = tid >> 6;
    const int bpd  = (ndir == 2) ? 128 : 256;
    const int dir  = blockIdx.x / bpd;
    const int blk  = blockIdx.x - dir * bpd;
    const int m0   = blk * 4;
    const int rev  = (rev_mask >> dir) & 1;
    const float* xw  = dir ? xw1  : xw0;
    const float* Whh = dir ? Whh1 : Whh0;
    const int dcol = dir * H_T;
    const int b = tid & 63;
    const int j = tid >> 6;

    int* myflag = bar + blockIdx.x * 32;
    const int* pollflag = bar + (dir * bpd + (tid < bpd ? tid : 0)) * 32;
    const bool polls = (tid < bpd);

    // ---- B-fragments: Whh rows in registers, bf16 ----
    const int n  = lane & 15;           // (gate,cell) = (n>>2, n&3)
    const int kg = lane >> 4;
    const int wr = (n >> 2) * H_T + m0 + (n & 3);
    s16x8 wfr[KST];
#pragma unroll
    for (int ks = 0; ks < KST; ++ks) {
        const float* wp = Whh + (size_t)wr * H_T + ks * 32 + kg * 8;
        const float4 lo = *reinterpret_cast<const float4*>(wp);
        const float4 hi = *reinterpret_cast<const float4*>(wp + 4);
        s16x8 rr;
        rr[0] = (short)f2bf(lo.x); rr[1] = (short)f2bf(lo.y);
        rr[2] = (short)f2bf(lo.z); rr[3] = (short)f2bf(lo.w);
        rr[4] = (short)f2bf(hi.x); rr[5] = (short)f2bf(hi.y);
        rr[6] = (short)f2bf(hi.z); rr[7] = (short)f2bf(hi.w);
        wfr[ks] = rr;
    }

    float c  = c0 ? c0[(size_t)b * HSTR + dcol + m0 + j] : 0.f;
    float hn = 0.f;
    const int rA = w * 16 + n;
    const int rAx = rA & 7;

    for (int s = 0; s < T; ++s) {
        const int tt = rev ? (T - 1 - s) : s;

        // coalesced xw gate loads: layout (tt, 4H, b)
        const float* xb = xw + ((size_t)tt * (4 * H_T) + m0 + j) * 64 + b;
        float xg0 = g_load1(xb);
        float xg1 = g_load1(xb + (size_t)H_T * 64);
        float xg2 = g_load1(xb + (size_t)2 * H_T * 64);
        float xg3 = g_load1(xb + (size_t)3 * H_T * 64);

        // single-hop: wait for all producers of step s-1
        if (s > 0) {
            int ok = polls ? 0 : 1;
            for (;;) {
                if (!ok) ok = (sc_load1(pollflag) >= s) ? 1 : 0;
                if (__syncthreads_and(ok)) break;
            }
        }

        const unsigned short* hb;
        size_t tofs;
        if (s == 0) { hb = h0b; tofs = 0; }
        else {
            const int tp = rev ? (tt + 1) : (tt - 1);
            hb = hist; tofs = (size_t)tp * (64 * 1024);
        }

        float p0 = 0.f, p1 = 0.f, p2 = 0.f, p3 = 0.f;
        if (hb) {
            // ---- stage h tile: sc_load4 -> XOR-swizzled LDS, 2-deep counted pipeline ----
            f4_t bufA[8], bufB[8];
            auto issue = [&](f4_t (&bf)[8], int bt) {
#pragma unroll
                for (int jj = 0; jj < 8; ++jj) {
                    const int idx = (bt * 8 + jj) * 256 + tid;
                    const int rr_ = idx / CH, cc_ = idx % CH;
                    bf[jj] = sc_load4(hb + tofs + (size_t)rr_ * 1024 + dcol + cc_ * 8);
                }
            };
            auto writeb = [&](const f4_t (&bf)[8], int bt) {
#pragma unroll
                for (int jj = 0; jj < 8; ++jj) {
                    const int idx = (bt * 8 + jj) * 256 + tid;
                    const int rr_ = idx / CH, cc_ = idx % CH;
                    const int off = rr_ * (2 * H_T) + ((cc_ ^ (rr_ & 7)) << 4);
                    *(f4_t*)((char*)h_lds + off) = bf[jj];
                }
            };
            issue(bufA, 0);
            if (NB > 1) issue(bufB, 1);
#pragma unroll
            for (int bt = 0; bt < NB; ++bt) {
                if (bt + 1 < NB) wait_vm8(); else wait_vm0();
                if (bt & 1) writeb(bufB, bt); else writeb(bufA, bt);
                if (bt + 2 < NB) { if (bt & 1) issue(bufB, bt + 2); else issue(bufA, bt + 2); }
            }
            __syncthreads();

            // ---- MFMA: D[batch][n] += h[batch][k] * W[wr(n)][k] ----
            f32x4 acc = {0.f, 0.f, 0.f, 0.f};
#pragma unroll
            for (int ks = 0; ks < KST; ++ks) {
                const int cc_ = ks * 4 + kg;
                const int off = rA * (2 * H_T) + ((cc_ ^ rAx) << 4);
                const bf16x8 a = __builtin_bit_cast(bf16x8,
                    *(const s16x8*)((const char*)h_lds + off));
                acc = __builtin_amdgcn_mfma_f32_16x16x32_bf16(
                    a, __builtin_bit_cast(bf16x8, wfr[ks]), acc, 0, 0, 0);
            }
            // ---- exchange D -> (b, gate) layout ----
            __syncthreads();
#pragma unroll
            for (int rg = 0; rg < 4; ++rg)
                pre[w * 16 + kg * 4 + rg][n] = acc[rg];
            __syncthreads();
            p0 = pre[b][0 + j]; p1 = pre[b][4 + j];
            p2 = pre[b][8 + j]; p3 = pre[b][12 + j];
        }

        asm volatile("s_waitcnt vmcnt(0)"
                     : "+v"(xg0), "+v"(xg1), "+v"(xg2), "+v"(xg3) :: "memory");

        const float ig = sigmoidf_(p0 + xg0);
        const float fg = sigmoidf_(p1 + xg1);
        const float gg = tanhf(p2 + xg2);
        const float og = sigmoidf_(p3 + xg3);
        c  = fg * c + ig * gg;
        hn = og * tanhf(c);

        // pack 4 cells x 64 batches in LDS -> 64 coherent 8B stores
        hpack[b][j] = f2bf(hn);
        __syncthreads();
        if (tid < 64) {
            const i32x2 v2 = *reinterpret_cast<const i32x2*>(&hpack[tid][0]);
            sc_store8(hist + (size_t)tt * (64 * 1024) + (size_t)tid * 1024 + dcol + m0, v2);
        }
        wait_vm0();
        __syncthreads();          // ALL threads' stores drained before flag
        if (s + 1 < T && tid == 0) sc_store_int(myflag, s + 1);
    }

    if (hsb) hsb[(size_t)b * 1024 + dcol + m0 + j] = f2bf(hn);
    if (csd) csd[(size_t)b * HSTR + dcol + m0 + j] = c;
}

// ---------------- in-place row log-softmax (float4) ----------------
__global__ __launch_bounds__(256) void logsoftmax_kernel(float* __restrict__ x, int n4)
{
    const int tid = threadIdx.x;
    float4* p = reinterpret_cast<float4*>(x + (size_t)blockIdx.x * (n4 * 4));
    float m = -3.0e38f, s = 0.f;
    for (int cc = tid; cc < n4; cc += 256) {
        const float4 v = p[cc];
        const float vv[4] = { v.x, v.y, v.z, v.w };
#pragma unroll
        for (int e = 0; e < 4; ++e) {
            const float z = vv[e];
            if (z > m) { s = s * expf(m - z) + 1.f; m = z; }
            else       { s += expf(z - m); }
        }
    }
    __shared__ float ms[256], ss[256];
    ms[tid] = m; ss[tid] = s;
    __syncthreads();
    for (int off = 128; off > 0; off >>= 1) {
        if (tid < off) {
            const float m2 = ms[tid + off], s2 = ss[tid + off];
            const float m1 = ms[tid],       s1 = ss[tid];
            const float M = fmaxf(m1, m2);
            ss[tid] = s1 * expf(m1 - M) + s2 * expf(m2 - M);
            ms[tid] = M;
        }
        __syncthreads();
    }
    const float ML = ms[0] + logf(ss[0]);
    for (int cc = tid; cc < n4; cc += 256) {
        float4 v = p[cc];
        v.x -= ML; v.y -= ML; v.z -= ML; v.w -= ML;
        p[cc] = v;
    }
}

// ---------------- host-side orchestration ----------------
extern "C" void kernel_launch(void* const* d_in, const int* in_sizes, int n_in,
                              void* d_out, int out_size, void* d_ws, size_t ws_size,
                              hipStream_t stream)
{
    const int*   sent  = (const int*)d_in[0];
    const int*   targ  = (const int*)d_in[1];
    const float* emb   = (const float*)d_in[2];
    const float* e0Wih = (const float*)d_in[3];
    const float* e0Whh = (const float*)d_in[4];
    const float* e0bih = (const float*)d_in[5];
    const float* e0bhh = (const float*)d_in[6];
    const float* e1Wih = (const float*)d_in[7];
    const float* e1Whh = (const float*)d_in[8];
    const float* e1bih = (const float*)d_in[9];
    const float* e1bhh = (const float*)d_in[10];
    const float* d0Wih = (const float*)d_in[11];
    const float* d0Whh = (const float*)d_in[12];
    const float* d0bih = (const float*)d_in[13];
    const float* d0bhh = (const float*)d_in[14];
    const float* d1Wih = (const float*)d_in[15];
    const float* d1Whh = (const float*)d_in[16];
    const float* d1bih = (const float*)d_in[17];
    const float* d1bhh = (const float*)d_in[18];
    const float* Wout  = (const float*)d_in[19];
    const float* bout  = (const float*)d_in[20];

    float* ws  = (float*)d_ws;
    float* xwA = ws + WS_XWA;
    float* xwB = ws + WS_XWB;
    float* cs  = ws + WS_CS;
    int*   bar = (int*)(ws + WS_BAR);
    unsigned short* ub    = (unsigned short*)(ws + WS_BF);
    unsigned short* x0b   = ub + U_X0B;
    unsigned short* h_e0  = ub + U_HE0;
    unsigned short* h_e1  = ub + U_HE1;
    unsigned short* h_d0  = ub + U_HD0;
    unsigned short* h_d1  = ub + U_HD1;
    unsigned short* hsb   = ub + U_HSB;
    unsigned short* e0Wb  = ub + U_E0W;
    unsigned short* e1Wb  = ub + U_E1W;
    unsigned short* d0Wb  = ub + U_D0W;
    unsigned short* d1Wb  = ub + U_D1W;
    unsigned short* Woutb = (unsigned short*)xwA;   // reused after dec0 scan
    float* out = (float*)d_out;

    hipMemsetAsync(bar, 0, 4 * 8192 * sizeof(int), stream);

    // ---- weight conversions (fp32 -> bf16) ----
    f2b_kernel<<<256, 256, 0, stream>>>(e0Wih, e0Wb, 1048576 / 4);
    f2b_kernel<<<512, 256, 0, stream>>>(e1Wih, e1Wb, 4194304 / 4);
    f2b_kernel<<<256, 256, 0, stream>>>(d0Wih, d0Wb, 1048576 / 4);
    f2b_kernel<<<512, 256, 0, stream>>>(d1Wih, d1Wb, 4194304 / 4);

    // ---- encoder layer 0 ----
    embed_src_kernel<<<S_LEN * BSZ, 64, 0, stream>>>(sent, emb, x0b);
    gemm_bf16_kernel<<<64 * 16, 256, 0, stream>>>(x0b, e0Wb, e0bih, e0bhh, xwA,
                                                  S_LEN * BSZ, 2048, EMBD, 16, 1);
    gemm_bf16_kernel<<<64 * 16, 256, 0, stream>>>(x0b, e0Wb + 2048ull * 256,
                                                  e0bih + 2048, e0bhh + 2048, xwB,
                                                  S_LEN * BSZ, 2048, EMBD, 16, 1);
    lstm_mfma_scan<512><<<256, 256, 0, stream>>>(xwA, xwB, e0Whh, e0Whh + 2048ull * 512,
                                                 nullptr, nullptr, h_e0,
                                                 hsb, cs, S_LEN, 2, 2, bar);
    // ---- encoder layer 1 (final states only) ----
    gemm_bf16_kernel<<<64 * 16, 256, 0, stream>>>(h_e0, e1Wb, e1bih, e1bhh, xwA,
                                                  S_LEN * BSZ, 2048, 2 * HID_, 16, 1);
    gemm_bf16_kernel<<<64 * 16, 256, 0, stream>>>(h_e0, e1Wb + 2048ull * 1024,
                                                  e1bih + 2048, e1bhh + 2048, xwB,
                                                  S_LEN * BSZ, 2048, 2 * HID_, 16, 1);
    lstm_mfma_scan<512><<<256, 256, 0, stream>>>(xwA, xwB, e1Whh, e1Whh + 2048ull * 512,
                                                 nullptr, nullptr, h_e1,
                                                 hsb + 65536, cs + 65536,
                                                 S_LEN, 2, 2, bar + 8192);
    // ---- decoder layer 0 ----
    embed_dec_kernel<<<T_LEN * BSZ, 64, 0, stream>>>(sent, targ, emb, x0b);
    gemm_bf16_kernel<<<32 * 32, 256, 0, stream>>>(x0b, d0Wb, d0bih, d0bhh, xwA,
                                                  T_LEN * BSZ, 4 * DHID_, EMBD, 32, 1);
    lstm_mfma_scan<1024><<<256, 256, 0, stream>>>(xwA, nullptr, d0Whh, nullptr,
                                                  hsb, cs, h_d0,
                                                  nullptr, nullptr, T_LEN, 1, 0,
                                                  bar + 2 * 8192);
    // ---- Wout -> bf16 (xwA region free after dec0 scan; stream-ordered) ----
    f2b_kernel<<<2048, 256, 0, stream>>>(Wout, Woutb, (VOC_ * DHID_) / 4);
    // ---- decoder layer 1 ----
    gemm_bf16_kernel<<<32 * 32, 256, 0, stream>>>(h_d0, d1Wb, d1bih, d1bhh, xwB,
                                                  T_LEN * BSZ, 4 * DHID_, DHID_, 32, 1);
    lstm_mfma_scan<1024><<<256, 256, 0, stream>>>(xwB, nullptr, d1Whh, nullptr,
                                                  hsb + 65536, cs + 65536, h_d1,
                                                  nullptr, nullptr, T_LEN, 1, 0,
                                                  bar + 3 * 8192);
    // ---- vocab projection + log-softmax ----
    gemm_bf16_kernel<<<32 * 250, 256, 0, stream>>>(h_d1, Woutb, bout, nullptr, out,
                                                   T_LEN * BSZ, VOC_, DHID_, 250, 0);
    logsoftmax_kernel<<<T_LEN * BSZ, 256, 0, stream>>>(out, VOC_ / 4);
}